// Round 1
// baseline (3779.512 us; speedup 1.0000x reference)
//
#include <hip/hip_runtime.h>

#define F_IN 20
#define F_HID 64
#define F_OUT 2

// ---------------- degree ----------------
__global__ void k_deg_init(float* __restrict__ deg, int n) {
    int i = blockIdx.x * blockDim.x + threadIdx.x;
    if (i < n) deg[i] = 1.0f;  // self-loop
}

__global__ void k_deg_count(const int* __restrict__ dst, float* __restrict__ deg, int e) {
    int i = blockIdx.x * blockDim.x + threadIdx.x;
    if (i < e) atomicAdd(&deg[dst[i]], 1.0f);
}

// dinv = rsqrt(deg); agg[i] = x[i] * dinv[i]^2  (self-loop term of layer-1 agg)
__global__ void k_dinv_selfagg(const float* __restrict__ x, const float* __restrict__ deg,
                               float* __restrict__ dinv, float* __restrict__ agg, int n) {
    int i = blockIdx.x * blockDim.x + threadIdx.x;
    if (i >= n) return;
    float d = rsqrtf(deg[i]);
    dinv[i] = d;
    float d2 = d * d;
    const float4* xr = (const float4*)(x + (size_t)i * F_IN);
    float4* ar = (float4*)(agg + (size_t)i * F_IN);
#pragma unroll
    for (int k = 0; k < 5; ++k) {
        float4 v = xr[k];
        v.x *= d2; v.y *= d2; v.z *= d2; v.w *= d2;
        ar[k] = v;
    }
}

// layer-1 edge aggregation over raw x (20 features)
__global__ void k_edge1(const int* __restrict__ src, const int* __restrict__ dst,
                        const float* __restrict__ x, const float* __restrict__ dinv,
                        float* __restrict__ agg, int e) {
    int i = blockIdx.x * blockDim.x + threadIdx.x;
    if (i >= e) return;
    int s = src[i], d = dst[i];
    float w = dinv[s] * dinv[d];
    const float4* xr = (const float4*)(x + (size_t)s * F_IN);
    float* ad = agg + (size_t)d * F_IN;
#pragma unroll
    for (int k = 0; k < 5; ++k) {
        float4 v = xr[k];
        atomicAdd(&ad[k * 4 + 0], v.x * w);
        atomicAdd(&ad[k * 4 + 1], v.y * w);
        atomicAdd(&ad[k * 4 + 2], v.z * w);
        atomicAdd(&ad[k * 4 + 3], v.w * w);
    }
}

// fused: h = relu(agg@W1 + b1); t = h@W2; ts = t*dinv; out init = b2 + t*dinv^2
__global__ void k_mlp(const float* __restrict__ agg, const float* __restrict__ W1,
                      const float* __restrict__ b1, const float* __restrict__ W2,
                      const float* __restrict__ b2, const float* __restrict__ dinv,
                      float* __restrict__ ts, float* __restrict__ out, int n) {
    __shared__ float W1s[F_IN * F_HID];
    __shared__ float b1s[F_HID];
    __shared__ float W2s[F_HID * F_OUT];
    for (int t = threadIdx.x; t < F_IN * F_HID; t += blockDim.x) W1s[t] = W1[t];
    if (threadIdx.x < F_HID) b1s[threadIdx.x] = b1[threadIdx.x];
    if (threadIdx.x < F_HID * F_OUT) W2s[threadIdx.x] = W2[threadIdx.x];
    __syncthreads();
    int i = blockIdx.x * blockDim.x + threadIdx.x;
    if (i >= n) return;
    float xa[F_IN];
    const float4* ar = (const float4*)(agg + (size_t)i * F_IN);
#pragma unroll
    for (int k = 0; k < 5; ++k) {
        float4 v = ar[k];
        xa[k * 4 + 0] = v.x; xa[k * 4 + 1] = v.y;
        xa[k * 4 + 2] = v.z; xa[k * 4 + 3] = v.w;
    }
    float t0 = 0.0f, t1 = 0.0f;
#pragma unroll 8
    for (int j = 0; j < F_HID; ++j) {
        float acc = b1s[j];
#pragma unroll
        for (int k = 0; k < F_IN; ++k) acc = fmaf(xa[k], W1s[k * F_HID + j], acc);
        float h = fmaxf(acc, 0.0f);
        t0 = fmaf(h, W2s[j * F_OUT + 0], t0);
        t1 = fmaf(h, W2s[j * F_OUT + 1], t1);
    }
    float dv = dinv[i];
    ts[(size_t)i * 2 + 0] = t0 * dv;           // pre-scaled by dinv[src]
    ts[(size_t)i * 2 + 1] = t1 * dv;
    out[(size_t)i * 2 + 0] = b2[0] + t0 * dv * dv;  // bias + self-loop
    out[(size_t)i * 2 + 1] = b2[1] + t1 * dv * dv;
}

// layer-2 edge aggregation over t (2 features)
__global__ void k_edge2(const int* __restrict__ src, const int* __restrict__ dst,
                        const float* __restrict__ ts, const float* __restrict__ dinv,
                        float* __restrict__ out, int e) {
    int i = blockIdx.x * blockDim.x + threadIdx.x;
    if (i >= e) return;
    int s = src[i], d = dst[i];
    float wd = dinv[d];
    float2 t = *(const float2*)(ts + (size_t)s * 2);
    atomicAdd(&out[(size_t)d * 2 + 0], t.x * wd);
    atomicAdd(&out[(size_t)d * 2 + 1], t.y * wd);
}

extern "C" void kernel_launch(void* const* d_in, const int* in_sizes, int n_in,
                              void* d_out, int out_size, void* d_ws, size_t ws_size,
                              hipStream_t stream) {
    const float* x  = (const float*)d_in[0];
    const int*   ei = (const int*)d_in[1];
    const float* W1 = (const float*)d_in[2];
    const float* b1 = (const float*)d_in[3];
    const float* W2 = (const float*)d_in[4];
    const float* b2 = (const float*)d_in[5];
    float* out = (float*)d_out;

    const int n = in_sizes[0] / F_IN;   // 100000
    const int e = in_sizes[1] / 2;      // 3200000
    const int* src = ei;
    const int* dst = ei + e;

    float* deg  = (float*)d_ws;          // n
    float* dinv = deg + n;               // n
    float* ts   = dinv + n;              // 2n
    float* agg  = ts + 2 * (size_t)n;    // 20n

    const int B = 256;
    const int gn = (n + B - 1) / B;
    const int ge = (e + B - 1) / B;

    k_deg_init<<<gn, B, 0, stream>>>(deg, n);
    k_deg_count<<<ge, B, 0, stream>>>(dst, deg, e);
    k_dinv_selfagg<<<gn, B, 0, stream>>>(x, deg, dinv, agg, n);
    k_edge1<<<ge, B, 0, stream>>>(src, dst, x, dinv, agg, e);
    k_mlp<<<gn, B, 0, stream>>>(agg, W1, b1, W2, b2, dinv, ts, out, n);
    k_edge2<<<ge, B, 0, stream>>>(src, dst, ts, dinv, out, e);
}

// Round 2
// 643.278 us; speedup vs baseline: 5.8754x; 5.8754x over previous
//
#include <hip/hip_runtime.h>

#define F_IN 20
#define F_HID 64
#define F_OUT 2

// ============================ CSR path ============================

__global__ void k_zero_i(int* __restrict__ p, int n) {
    int i = blockIdx.x * blockDim.x + threadIdx.x;
    if (i < n) p[i] = 0;
}

__global__ void k_hist(const int* __restrict__ dst, int* __restrict__ counts, int e) {
    int i = blockIdx.x * blockDim.x + threadIdx.x;
    if (i < e) atomicAdd(&counts[dst[i]], 1);
}

// single-workgroup exclusive scan over counts -> row_ptr (and cursor copy)
__global__ __launch_bounds__(1024) void k_scan(const int* __restrict__ counts,
                                               int* __restrict__ row_ptr,
                                               int* __restrict__ cursor, int n) {
    __shared__ int warp_sums[16];
    __shared__ int carry_s;
    const int tid = threadIdx.x;
    const int lane = tid & 63, wid = tid >> 6;
    if (tid == 0) carry_s = 0;
    __syncthreads();
    for (int base = 0; base < n; base += 1024) {
        int i = base + tid;
        int v = (i < n) ? counts[i] : 0;
        int sv = v;
#pragma unroll
        for (int off = 1; off < 64; off <<= 1) {
            int t = __shfl_up(sv, off, 64);
            if (lane >= off) sv += t;
        }
        if (lane == 63) warp_sums[wid] = sv;
        __syncthreads();
        if (wid == 0 && lane < 16) {
            int ws = warp_sums[lane];
#pragma unroll
            for (int off = 1; off < 16; off <<= 1) {
                int t = __shfl_up(ws, off, 16);
                if (lane >= off) ws += t;
            }
            warp_sums[lane] = ws;
        }
        __syncthreads();
        int wofs = (wid > 0) ? warp_sums[wid - 1] : 0;
        int excl = carry_s + wofs + sv - v;
        if (i < n) { row_ptr[i] = excl; cursor[i] = excl; }
        __syncthreads();                      // everyone has read carry_s / warp_sums
        if (tid == 0) carry_s += warp_sums[15];
        __syncthreads();
    }
    if (tid == 0) row_ptr[n] = carry_s;
}

__global__ void k_fill(const int* __restrict__ src, const int* __restrict__ dst,
                       int* __restrict__ cursor, int* __restrict__ edge_src, int e) {
    int i = blockIdx.x * blockDim.x + threadIdx.x;
    if (i >= e) return;
    int s = src[i], d = dst[i];
    int pos = atomicAdd(&cursor[d], 1);
    edge_src[pos] = s;
}

__global__ void k_dinv(const int* __restrict__ counts, float* __restrict__ dinv, int n) {
    int i = blockIdx.x * blockDim.x + threadIdx.x;
    if (i < n) dinv[i] = rsqrtf(1.0f + (float)counts[i]);  // +1 self-loop
}

// per-node gather of x over in-edges + fused MLP -> ts (pre-scaled by dinv[node])
__global__ void k_gather_mlp(const int* __restrict__ row_ptr, const int* __restrict__ edge_src,
                             const float* __restrict__ x, const float* __restrict__ dinv,
                             const float* __restrict__ W1, const float* __restrict__ b1,
                             const float* __restrict__ W2, float* __restrict__ ts, int n) {
    __shared__ float W1s[F_IN * F_HID];
    __shared__ float b1s[F_HID];
    __shared__ float W2s[F_HID * F_OUT];
    for (int t = threadIdx.x; t < F_IN * F_HID; t += blockDim.x) W1s[t] = W1[t];
    if (threadIdx.x < F_HID) b1s[threadIdx.x] = b1[threadIdx.x];
    if (threadIdx.x < F_HID * F_OUT) W2s[threadIdx.x] = W2[threadIdx.x];
    __syncthreads();
    int i = blockIdx.x * blockDim.x + threadIdx.x;
    if (i >= n) return;

    float dv = dinv[i];
    float acc[F_IN];
    {   // self-loop: x[i] * dv^2
        float d2 = dv * dv;
        const float4* xr = (const float4*)(x + (size_t)i * F_IN);
#pragma unroll
        for (int k = 0; k < 5; ++k) {
            float4 v = xr[k];
            acc[k * 4 + 0] = v.x * d2; acc[k * 4 + 1] = v.y * d2;
            acc[k * 4 + 2] = v.z * d2; acc[k * 4 + 3] = v.w * d2;
        }
    }
    int jb = row_ptr[i], je = row_ptr[i + 1];
    for (int j = jb; j < je; ++j) {
        int s = edge_src[j];
        float w = dinv[s] * dv;
        const float4* xr = (const float4*)(x + (size_t)s * F_IN);
#pragma unroll
        for (int k = 0; k < 5; ++k) {
            float4 v = xr[k];
            acc[k * 4 + 0] = fmaf(v.x, w, acc[k * 4 + 0]);
            acc[k * 4 + 1] = fmaf(v.y, w, acc[k * 4 + 1]);
            acc[k * 4 + 2] = fmaf(v.z, w, acc[k * 4 + 2]);
            acc[k * 4 + 3] = fmaf(v.w, w, acc[k * 4 + 3]);
        }
    }
    float t0 = 0.0f, t1 = 0.0f;
#pragma unroll 8
    for (int j = 0; j < F_HID; ++j) {
        float a = b1s[j];
#pragma unroll
        for (int k = 0; k < F_IN; ++k) a = fmaf(acc[k], W1s[k * F_HID + j], a);
        float h = fmaxf(a, 0.0f);
        t0 = fmaf(h, W2s[j * F_OUT + 0], t0);
        t1 = fmaf(h, W2s[j * F_OUT + 1], t1);
    }
    ts[(size_t)i * 2 + 0] = t0 * dv;   // t * dinv[node]
    ts[(size_t)i * 2 + 1] = t1 * dv;
}

// layer-2 per-node gather of ts: out = b2 + dinv[i]*(ts[i] + sum_{s in N(i)} ts[s])
__global__ void k_gather2(const int* __restrict__ row_ptr, const int* __restrict__ edge_src,
                          const float* __restrict__ ts, const float* __restrict__ dinv,
                          const float* __restrict__ b2, float* __restrict__ out, int n) {
    int i = blockIdx.x * blockDim.x + threadIdx.x;
    if (i >= n) return;
    float dv = dinv[i];
    float2 t = *(const float2*)(ts + (size_t)i * 2);
    float a0 = t.x, a1 = t.y;
    int jb = row_ptr[i], je = row_ptr[i + 1];
    for (int j = jb; j < je; ++j) {
        int s = edge_src[j];
        float2 v = *(const float2*)(ts + (size_t)s * 2);
        a0 += v.x; a1 += v.y;
    }
    out[(size_t)i * 2 + 0] = b2[0] + a0 * dv;
    out[(size_t)i * 2 + 1] = b2[1] + a1 * dv;
}

// ===================== fallback (round-1 atomic) path =====================

__global__ void k_deg_init(float* __restrict__ deg, int n) {
    int i = blockIdx.x * blockDim.x + threadIdx.x;
    if (i < n) deg[i] = 1.0f;
}
__global__ void k_deg_count(const int* __restrict__ dst, float* __restrict__ deg, int e) {
    int i = blockIdx.x * blockDim.x + threadIdx.x;
    if (i < e) atomicAdd(&deg[dst[i]], 1.0f);
}
__global__ void k_dinv_selfagg(const float* __restrict__ x, const float* __restrict__ deg,
                               float* __restrict__ dinv, float* __restrict__ agg, int n) {
    int i = blockIdx.x * blockDim.x + threadIdx.x;
    if (i >= n) return;
    float d = rsqrtf(deg[i]);
    dinv[i] = d;
    float d2 = d * d;
    const float4* xr = (const float4*)(x + (size_t)i * F_IN);
    float4* ar = (float4*)(agg + (size_t)i * F_IN);
#pragma unroll
    for (int k = 0; k < 5; ++k) {
        float4 v = xr[k];
        v.x *= d2; v.y *= d2; v.z *= d2; v.w *= d2;
        ar[k] = v;
    }
}
__global__ void k_edge1(const int* __restrict__ src, const int* __restrict__ dst,
                        const float* __restrict__ x, const float* __restrict__ dinv,
                        float* __restrict__ agg, int e) {
    int i = blockIdx.x * blockDim.x + threadIdx.x;
    if (i >= e) return;
    int s = src[i], d = dst[i];
    float w = dinv[s] * dinv[d];
    const float4* xr = (const float4*)(x + (size_t)s * F_IN);
    float* ad = agg + (size_t)d * F_IN;
#pragma unroll
    for (int k = 0; k < 5; ++k) {
        float4 v = xr[k];
        atomicAdd(&ad[k * 4 + 0], v.x * w);
        atomicAdd(&ad[k * 4 + 1], v.y * w);
        atomicAdd(&ad[k * 4 + 2], v.z * w);
        atomicAdd(&ad[k * 4 + 3], v.w * w);
    }
}
__global__ void k_mlp_fb(const float* __restrict__ agg, const float* __restrict__ W1,
                         const float* __restrict__ b1, const float* __restrict__ W2,
                         const float* __restrict__ b2, const float* __restrict__ dinv,
                         float* __restrict__ ts, float* __restrict__ out, int n) {
    __shared__ float W1s[F_IN * F_HID];
    __shared__ float b1s[F_HID];
    __shared__ float W2s[F_HID * F_OUT];
    for (int t = threadIdx.x; t < F_IN * F_HID; t += blockDim.x) W1s[t] = W1[t];
    if (threadIdx.x < F_HID) b1s[threadIdx.x] = b1[threadIdx.x];
    if (threadIdx.x < F_HID * F_OUT) W2s[threadIdx.x] = W2[threadIdx.x];
    __syncthreads();
    int i = blockIdx.x * blockDim.x + threadIdx.x;
    if (i >= n) return;
    float xa[F_IN];
    const float4* ar = (const float4*)(agg + (size_t)i * F_IN);
#pragma unroll
    for (int k = 0; k < 5; ++k) {
        float4 v = ar[k];
        xa[k * 4 + 0] = v.x; xa[k * 4 + 1] = v.y;
        xa[k * 4 + 2] = v.z; xa[k * 4 + 3] = v.w;
    }
    float t0 = 0.0f, t1 = 0.0f;
#pragma unroll 8
    for (int j = 0; j < F_HID; ++j) {
        float a = b1s[j];
#pragma unroll
        for (int k = 0; k < F_IN; ++k) a = fmaf(xa[k], W1s[k * F_HID + j], a);
        float h = fmaxf(a, 0.0f);
        t0 = fmaf(h, W2s[j * F_OUT + 0], t0);
        t1 = fmaf(h, W2s[j * F_OUT + 1], t1);
    }
    float dv = dinv[i];
    ts[(size_t)i * 2 + 0] = t0 * dv;
    ts[(size_t)i * 2 + 1] = t1 * dv;
    out[(size_t)i * 2 + 0] = b2[0] + t0 * dv * dv;
    out[(size_t)i * 2 + 1] = b2[1] + t1 * dv * dv;
}
__global__ void k_edge2(const int* __restrict__ src, const int* __restrict__ dst,
                        const float* __restrict__ ts, const float* __restrict__ dinv,
                        float* __restrict__ out, int e) {
    int i = blockIdx.x * blockDim.x + threadIdx.x;
    if (i >= e) return;
    int s = src[i], d = dst[i];
    float wd = dinv[d];
    float2 t = *(const float2*)(ts + (size_t)s * 2);
    atomicAdd(&out[(size_t)d * 2 + 0], t.x * wd);
    atomicAdd(&out[(size_t)d * 2 + 1], t.y * wd);
}

// ============================ launch ============================

extern "C" void kernel_launch(void* const* d_in, const int* in_sizes, int n_in,
                              void* d_out, int out_size, void* d_ws, size_t ws_size,
                              hipStream_t stream) {
    const float* x  = (const float*)d_in[0];
    const int*   ei = (const int*)d_in[1];
    const float* W1 = (const float*)d_in[2];
    const float* b1 = (const float*)d_in[3];
    const float* W2 = (const float*)d_in[4];
    const float* b2 = (const float*)d_in[5];
    float* out = (float*)d_out;

    const int n = in_sizes[0] / F_IN;   // 100000
    const int e = in_sizes[1] / 2;      // 3200000
    const int* src = ei;
    const int* dst = ei + e;

    const int B = 256;
    const int gn = (n + B - 1) / B;
    const int ge = (e + B - 1) / B;

    // CSR layout in d_ws
    size_t need = (size_t)(6 * (size_t)n + 1 + (size_t)e) * 4;
    if (ws_size >= need) {
        int*   counts   = (int*)d_ws;                 // n
        int*   row_ptr  = counts + n;                 // n+1
        int*   cursor   = row_ptr + n + 1;            // n
        int*   edge_src = cursor + n;                 // e
        float* dinv     = (float*)(edge_src + e);     // n
        float* ts       = dinv + n;                   // 2n

        k_zero_i<<<gn, B, 0, stream>>>(counts, n);
        k_hist<<<ge, B, 0, stream>>>(dst, counts, e);
        k_scan<<<1, 1024, 0, stream>>>(counts, row_ptr, cursor, n);
        k_fill<<<ge, B, 0, stream>>>(src, dst, cursor, edge_src, e);
        k_dinv<<<gn, B, 0, stream>>>(counts, dinv, n);
        k_gather_mlp<<<gn, B, 0, stream>>>(row_ptr, edge_src, x, dinv, W1, b1, W2, ts, n);
        k_gather2<<<gn, B, 0, stream>>>(row_ptr, edge_src, ts, dinv, b2, out, n);
    } else {
        float* deg  = (float*)d_ws;          // n
        float* dinv = deg + n;               // n
        float* ts   = dinv + n;              // 2n
        float* agg  = ts + 2 * (size_t)n;    // 20n

        k_deg_init<<<gn, B, 0, stream>>>(deg, n);
        k_deg_count<<<ge, B, 0, stream>>>(dst, deg, e);
        k_dinv_selfagg<<<gn, B, 0, stream>>>(x, deg, dinv, agg, n);
        k_edge1<<<ge, B, 0, stream>>>(src, dst, x, dinv, agg, e);
        k_mlp_fb<<<gn, B, 0, stream>>>(agg, W1, b1, W2, b2, dinv, ts, out, n);
        k_edge2<<<ge, B, 0, stream>>>(src, dst, ts, dinv, out, e);
    }
}

// Round 3
// 580.506 us; speedup vs baseline: 6.5107x; 1.1081x over previous
//
#include <hip/hip_runtime.h>

#define F_IN 20
#define F_HID 64
#define F_OUT 2
#define BKT 256        // nodes per bucket
#define MAXNB 512      // max buckets the LDS arrays support
#define NWG_A 512      // scatter workgroups

// ===================== bucketed path =====================

__global__ void kz(int* __restrict__ g, int nb) {
    int i = blockIdx.x * blockDim.x + threadIdx.x;
    if (i < nb) g[i] = 0;
}

// coarse histogram of dst>>8 (LDS-aggregated, then tiny global merge)
__global__ __launch_bounds__(256) void kA0(const int* __restrict__ dst,
                                           int* __restrict__ gcount, int e) {
    __shared__ int c[MAXNB];
    for (int t = threadIdx.x; t < MAXNB; t += 256) c[t] = 0;
    __syncthreads();
    int stride = gridDim.x * blockDim.x;
    for (int i = blockIdx.x * blockDim.x + threadIdx.x; i < e; i += stride)
        atomicAdd(&c[dst[i] >> 8], 1);
    __syncthreads();
    for (int t = threadIdx.x; t < MAXNB; t += 256)
        if (c[t]) atomicAdd(&gcount[t], c[t]);
}

__global__ void kscan(const int* __restrict__ gcount, int* __restrict__ gbase,
                      int* __restrict__ gcursor, int nb) {
    if (threadIdx.x == 0) {
        int acc = 0;
        for (int b = 0; b < nb; ++b) { gbase[b] = acc; gcursor[b] = acc; acc += gcount[b]; }
        gbase[nb] = acc;
    }
}

// scatter edges into coarse buckets as packed words: (dst&255)<<20 | src
__global__ __launch_bounds__(256) void kA(const int* __restrict__ src, const int* __restrict__ dst,
                                          int* __restrict__ gcursor, int* __restrict__ bedge, int e) {
    __shared__ int cnt[MAXNB];
    __shared__ int wb[MAXNB];
    int per = (e + gridDim.x - 1) / gridDim.x;
    int lo = blockIdx.x * per, hi = min(e, lo + per);
    for (int t = threadIdx.x; t < MAXNB; t += 256) cnt[t] = 0;
    __syncthreads();
    for (int j = lo + threadIdx.x; j < hi; j += 256) atomicAdd(&cnt[dst[j] >> 8], 1);
    __syncthreads();
    for (int t = threadIdx.x; t < MAXNB; t += 256) {
        int c = cnt[t];
        if (c) wb[t] = atomicAdd(&gcursor[t], c);
    }
    __syncthreads();
    for (int j = lo + threadIdx.x; j < hi; j += 256) {
        int d = dst[j], s = src[j];
        int pos = atomicAdd(&wb[d >> 8], 1);
        bedge[pos] = ((d & (BKT - 1)) << 20) | s;
    }
}

// per-bucket degree histogram in LDS -> dinv
__global__ __launch_bounds__(256) void kdinv(const int* __restrict__ bedge, const int* __restrict__ gbase,
                                             float* __restrict__ dinv, int n) {
    __shared__ int c[BKT];
    const int b = blockIdx.x;
    c[threadIdx.x] = 0;
    __syncthreads();
    int lo = gbase[b], hi = gbase[b + 1];
    for (int j = lo + threadIdx.x; j < hi; j += 256)
        atomicAdd(&c[((unsigned)bedge[j]) >> 20], 1);
    __syncthreads();
    int node = (b << 8) + threadIdx.x;
    if (node < n) dinv[node] = rsqrtf(1.0f + (float)c[threadIdx.x]);
}

// layer-1: LDS-accumulated aggregation of x over bucket + fused MLP -> ts
__global__ __launch_bounds__(256) void kL1(const int* __restrict__ bedge, const int* __restrict__ gbase,
                                           const float* __restrict__ x, const float* __restrict__ dinv,
                                           const float* __restrict__ W1, const float* __restrict__ b1,
                                           const float* __restrict__ W2, float* __restrict__ ts, int n) {
    __shared__ float acc[BKT * 21];   // padded stride 21: conflict-free
    __shared__ float sdv[BKT];
    __shared__ float W1s[F_IN * F_HID];
    __shared__ float b1s[F_HID];
    __shared__ float W2s[F_HID * F_OUT];
    const int tid = threadIdx.x, b = blockIdx.x, base = b << 8;
    for (int t = tid; t < BKT * 21; t += 256) acc[t] = 0.0f;
    for (int t = tid; t < F_IN * F_HID; t += 256) W1s[t] = W1[t];
    if (tid < F_HID) b1s[tid] = b1[tid];
    if (tid < F_HID * F_OUT) W2s[tid] = W2[tid];
    { int node = base + tid; sdv[tid] = (node < n) ? dinv[node] : 0.0f; }
    __syncthreads();
    int lo = gbase[b], hi = gbase[b + 1];
    for (int j = lo + tid; j < hi; j += 256) {
        unsigned w = (unsigned)bedge[j];
        int s = (int)(w & 1048575u);
        int dl = (int)(w >> 20);
        float wt = dinv[s] * sdv[dl];
        const float4* xr = (const float4*)(x + (size_t)s * F_IN);
        float* ar = &acc[dl * 21];
#pragma unroll
        for (int k = 0; k < 5; ++k) {
            float4 v = xr[k];
            atomicAdd(&ar[k * 4 + 0], v.x * wt);
            atomicAdd(&ar[k * 4 + 1], v.y * wt);
            atomicAdd(&ar[k * 4 + 2], v.z * wt);
            atomicAdd(&ar[k * 4 + 3], v.w * wt);
        }
    }
    __syncthreads();
    int node = base + tid;
    if (node >= n) return;
    float dv = sdv[tid], d2 = dv * dv;
    float xa[F_IN];
    const float4* xr = (const float4*)(x + (size_t)node * F_IN);
#pragma unroll
    for (int k = 0; k < 5; ++k) {
        float4 v = xr[k];
        xa[k * 4 + 0] = acc[tid * 21 + k * 4 + 0] + v.x * d2;
        xa[k * 4 + 1] = acc[tid * 21 + k * 4 + 1] + v.y * d2;
        xa[k * 4 + 2] = acc[tid * 21 + k * 4 + 2] + v.z * d2;
        xa[k * 4 + 3] = acc[tid * 21 + k * 4 + 3] + v.w * d2;
    }
    float t0 = 0.0f, t1 = 0.0f;
#pragma unroll 8
    for (int j = 0; j < F_HID; ++j) {
        float a = b1s[j];
#pragma unroll
        for (int k = 0; k < F_IN; ++k) a = fmaf(xa[k], W1s[k * F_HID + j], a);
        float h = fmaxf(a, 0.0f);
        t0 = fmaf(h, W2s[j * F_OUT + 0], t0);
        t1 = fmaf(h, W2s[j * F_OUT + 1], t1);
    }
    *(float2*)(ts + (size_t)node * 2) = make_float2(t0 * dv, t1 * dv);
}

// layer-2: LDS-accumulated aggregation of ts over bucket -> out
__global__ __launch_bounds__(256) void kL2(const int* __restrict__ bedge, const int* __restrict__ gbase,
                                           const float* __restrict__ ts, const float* __restrict__ dinv,
                                           const float* __restrict__ b2, float* __restrict__ out, int n) {
    __shared__ float a0[BKT], a1[BKT];
    const int tid = threadIdx.x, b = blockIdx.x, base = b << 8;
    a0[tid] = 0.0f; a1[tid] = 0.0f;
    __syncthreads();
    int lo = gbase[b], hi = gbase[b + 1];
    for (int j = lo + tid; j < hi; j += 256) {
        unsigned w = (unsigned)bedge[j];
        int s = (int)(w & 1048575u);
        int dl = (int)(w >> 20);
        float2 t = *(const float2*)(ts + (size_t)s * 2);
        atomicAdd(&a0[dl], t.x);
        atomicAdd(&a1[dl], t.y);
    }
    __syncthreads();
    int node = base + tid;
    if (node >= n) return;
    float dv = dinv[node];
    float2 t = *(const float2*)(ts + (size_t)node * 2);
    float2 o = make_float2(b2[0] + (a0[tid] + t.x) * dv, b2[1] + (a1[tid] + t.y) * dv);
    *(float2*)(out + (size_t)node * 2) = o;
}

// ===================== fallback: round-2 CSR path =====================

__global__ void k_zero_i(int* __restrict__ p, int n) {
    int i = blockIdx.x * blockDim.x + threadIdx.x;
    if (i < n) p[i] = 0;
}
__global__ void k_hist(const int* __restrict__ dst, int* __restrict__ counts, int e) {
    int i = blockIdx.x * blockDim.x + threadIdx.x;
    if (i < e) atomicAdd(&counts[dst[i]], 1);
}
__global__ __launch_bounds__(1024) void k_scan(const int* __restrict__ counts,
                                               int* __restrict__ row_ptr,
                                               int* __restrict__ cursor, int n) {
    __shared__ int warp_sums[16];
    __shared__ int carry_s;
    const int tid = threadIdx.x;
    const int lane = tid & 63, wid = tid >> 6;
    if (tid == 0) carry_s = 0;
    __syncthreads();
    for (int base = 0; base < n; base += 1024) {
        int i = base + tid;
        int v = (i < n) ? counts[i] : 0;
        int sv = v;
#pragma unroll
        for (int off = 1; off < 64; off <<= 1) {
            int t = __shfl_up(sv, off, 64);
            if (lane >= off) sv += t;
        }
        if (lane == 63) warp_sums[wid] = sv;
        __syncthreads();
        if (wid == 0 && lane < 16) {
            int ws = warp_sums[lane];
#pragma unroll
            for (int off = 1; off < 16; off <<= 1) {
                int t = __shfl_up(ws, off, 16);
                if (lane >= off) ws += t;
            }
            warp_sums[lane] = ws;
        }
        __syncthreads();
        int wofs = (wid > 0) ? warp_sums[wid - 1] : 0;
        int excl = carry_s + wofs + sv - v;
        if (i < n) { row_ptr[i] = excl; cursor[i] = excl; }
        __syncthreads();
        if (tid == 0) carry_s += warp_sums[15];
        __syncthreads();
    }
    if (tid == 0) row_ptr[n] = carry_s;
}
__global__ void k_fill(const int* __restrict__ src, const int* __restrict__ dst,
                       int* __restrict__ cursor, int* __restrict__ edge_src, int e) {
    int i = blockIdx.x * blockDim.x + threadIdx.x;
    if (i >= e) return;
    int s = src[i], d = dst[i];
    int pos = atomicAdd(&cursor[d], 1);
    edge_src[pos] = s;
}
__global__ void k_dinv_fb(const int* __restrict__ counts, float* __restrict__ dinv, int n) {
    int i = blockIdx.x * blockDim.x + threadIdx.x;
    if (i < n) dinv[i] = rsqrtf(1.0f + (float)counts[i]);
}
__global__ void k_gather_mlp(const int* __restrict__ row_ptr, const int* __restrict__ edge_src,
                             const float* __restrict__ x, const float* __restrict__ dinv,
                             const float* __restrict__ W1, const float* __restrict__ b1,
                             const float* __restrict__ W2, float* __restrict__ ts, int n) {
    __shared__ float W1s[F_IN * F_HID];
    __shared__ float b1s[F_HID];
    __shared__ float W2s[F_HID * F_OUT];
    for (int t = threadIdx.x; t < F_IN * F_HID; t += blockDim.x) W1s[t] = W1[t];
    if (threadIdx.x < F_HID) b1s[threadIdx.x] = b1[threadIdx.x];
    if (threadIdx.x < F_HID * F_OUT) W2s[threadIdx.x] = W2[threadIdx.x];
    __syncthreads();
    int i = blockIdx.x * blockDim.x + threadIdx.x;
    if (i >= n) return;
    float dv = dinv[i];
    float acc[F_IN];
    {
        float d2 = dv * dv;
        const float4* xr = (const float4*)(x + (size_t)i * F_IN);
#pragma unroll
        for (int k = 0; k < 5; ++k) {
            float4 v = xr[k];
            acc[k * 4 + 0] = v.x * d2; acc[k * 4 + 1] = v.y * d2;
            acc[k * 4 + 2] = v.z * d2; acc[k * 4 + 3] = v.w * d2;
        }
    }
    int jb = row_ptr[i], je = row_ptr[i + 1];
    for (int j = jb; j < je; ++j) {
        int s = edge_src[j];
        float w = dinv[s] * dv;
        const float4* xr = (const float4*)(x + (size_t)s * F_IN);
#pragma unroll
        for (int k = 0; k < 5; ++k) {
            float4 v = xr[k];
            acc[k * 4 + 0] = fmaf(v.x, w, acc[k * 4 + 0]);
            acc[k * 4 + 1] = fmaf(v.y, w, acc[k * 4 + 1]);
            acc[k * 4 + 2] = fmaf(v.z, w, acc[k * 4 + 2]);
            acc[k * 4 + 3] = fmaf(v.w, w, acc[k * 4 + 3]);
        }
    }
    float t0 = 0.0f, t1 = 0.0f;
#pragma unroll 8
    for (int j = 0; j < F_HID; ++j) {
        float a = b1s[j];
#pragma unroll
        for (int k = 0; k < F_IN; ++k) a = fmaf(acc[k], W1s[k * F_HID + j], a);
        float h = fmaxf(a, 0.0f);
        t0 = fmaf(h, W2s[j * F_OUT + 0], t0);
        t1 = fmaf(h, W2s[j * F_OUT + 1], t1);
    }
    ts[(size_t)i * 2 + 0] = t0 * dv;
    ts[(size_t)i * 2 + 1] = t1 * dv;
}
__global__ void k_gather2(const int* __restrict__ row_ptr, const int* __restrict__ edge_src,
                          const float* __restrict__ ts, const float* __restrict__ dinv,
                          const float* __restrict__ b2, float* __restrict__ out, int n) {
    int i = blockIdx.x * blockDim.x + threadIdx.x;
    if (i >= n) return;
    float dv = dinv[i];
    float2 t = *(const float2*)(ts + (size_t)i * 2);
    float a0 = t.x, a1 = t.y;
    int jb = row_ptr[i], je = row_ptr[i + 1];
    for (int j = jb; j < je; ++j) {
        int s = edge_src[j];
        float2 v = *(const float2*)(ts + (size_t)s * 2);
        a0 += v.x; a1 += v.y;
    }
    out[(size_t)i * 2 + 0] = b2[0] + a0 * dv;
    out[(size_t)i * 2 + 1] = b2[1] + a1 * dv;
}

// ============================ launch ============================

extern "C" void kernel_launch(void* const* d_in, const int* in_sizes, int n_in,
                              void* d_out, int out_size, void* d_ws, size_t ws_size,
                              hipStream_t stream) {
    const float* x  = (const float*)d_in[0];
    const int*   ei = (const int*)d_in[1];
    const float* W1 = (const float*)d_in[2];
    const float* b1 = (const float*)d_in[3];
    const float* W2 = (const float*)d_in[4];
    const float* b2 = (const float*)d_in[5];
    float* out = (float*)d_out;

    const int n = in_sizes[0] / F_IN;
    const int e = in_sizes[1] / 2;
    const int* src = ei;
    const int* dst = ei + e;

    const int B = 256;
    const int gn = (n + B - 1) / B;
    const int ge = (e + B - 1) / B;

    const int NB = (n + BKT - 1) / BKT;
    size_t need_b = ((size_t)NB * 3 + 1 + (size_t)e + 3 * (size_t)n) * 4;

    if (n < (1 << 20) && NB <= MAXNB && ws_size >= need_b) {
        int*   gcount  = (int*)d_ws;            // NB
        int*   gbase   = gcount + NB;           // NB+1
        int*   gcursor = gbase + NB + 1;        // NB
        int*   bedge   = gcursor + NB;          // e
        float* dinv    = (float*)(bedge + e);   // n
        float* ts      = dinv + n;              // 2n

        kz<<<(NB + 255) / 256, 256, 0, stream>>>(gcount, NB);
        kA0<<<NWG_A, 256, 0, stream>>>(dst, gcount, e);
        kscan<<<1, 64, 0, stream>>>(gcount, gbase, gcursor, NB);
        kA<<<NWG_A, 256, 0, stream>>>(src, dst, gcursor, bedge, e);
        kdinv<<<NB, 256, 0, stream>>>(bedge, gbase, dinv, n);
        kL1<<<NB, 256, 0, stream>>>(bedge, gbase, x, dinv, W1, b1, W2, ts, n);
        kL2<<<NB, 256, 0, stream>>>(bedge, gbase, ts, dinv, b2, out, n);
    } else {
        int*   counts   = (int*)d_ws;
        int*   row_ptr  = counts + n;
        int*   cursor   = row_ptr + n + 1;
        int*   edge_src = cursor + n;
        float* dinv     = (float*)(edge_src + e);
        float* ts       = dinv + n;

        k_zero_i<<<gn, B, 0, stream>>>(counts, n);
        k_hist<<<ge, B, 0, stream>>>(dst, counts, e);
        k_scan<<<1, 1024, 0, stream>>>(counts, row_ptr, cursor, n);
        k_fill<<<ge, B, 0, stream>>>(src, dst, cursor, edge_src, e);
        k_dinv_fb<<<gn, B, 0, stream>>>(counts, dinv, n);
        k_gather_mlp<<<gn, B, 0, stream>>>(row_ptr, edge_src, x, dinv, W1, b1, W2, ts, n);
        k_gather2<<<gn, B, 0, stream>>>(row_ptr, edge_src, ts, dinv, b2, out, n);
    }
}

// Round 4
// 219.234 us; speedup vs baseline: 17.2396x; 2.6479x over previous
//
#include <hip/hip_runtime.h>

#define F_IN 20
#define F_HID 64
#define F_OUT 2
#define BKT 256        // nodes per bucket
#define MAXNB 512      // max buckets the LDS arrays support
#define NWG_A 512      // scatter workgroups
#define STAGE_MAX 14336 // per-bucket LDS edge staging capacity (56 KB)
#define G 4            // lanes per node in gather kernels

// ===================== bucketed + sorted path =====================

__global__ void kz(int* __restrict__ g, int nb) {
    int i = blockIdx.x * blockDim.x + threadIdx.x;
    if (i < nb) g[i] = 0;
}

// coarse histogram of dst>>8 (LDS-aggregated, then tiny global merge)
__global__ __launch_bounds__(256) void kA0(const int* __restrict__ dst,
                                           int* __restrict__ gcount, int e) {
    __shared__ int c[MAXNB];
    for (int t = threadIdx.x; t < MAXNB; t += 256) c[t] = 0;
    __syncthreads();
    int stride = gridDim.x * blockDim.x;
    for (int i = blockIdx.x * blockDim.x + threadIdx.x; i < e; i += stride)
        atomicAdd(&c[dst[i] >> 8], 1);
    __syncthreads();
    for (int t = threadIdx.x; t < MAXNB; t += 256)
        if (c[t]) atomicAdd(&gcount[t], c[t]);
}

__global__ void kscan(const int* __restrict__ gcount, int* __restrict__ gbase,
                      int* __restrict__ gcursor, int* __restrict__ row_ptr,
                      int nb, int n) {
    if (threadIdx.x == 0) {
        int acc = 0;
        for (int b = 0; b < nb; ++b) { gbase[b] = acc; gcursor[b] = acc; acc += gcount[b]; }
        gbase[nb] = acc;
        row_ptr[n] = acc;
    }
}

// scatter edges into coarse buckets as packed words: (dst&255)<<20 | src
__global__ __launch_bounds__(256) void kA(const int* __restrict__ src, const int* __restrict__ dst,
                                          int* __restrict__ gcursor, int* __restrict__ bedge, int e) {
    __shared__ int cnt[MAXNB];
    __shared__ int wb[MAXNB];
    int per = (e + gridDim.x - 1) / gridDim.x;
    int lo = blockIdx.x * per, hi = min(e, lo + per);
    for (int t = threadIdx.x; t < MAXNB; t += 256) cnt[t] = 0;
    __syncthreads();
    for (int j = lo + threadIdx.x; j < hi; j += 256) atomicAdd(&cnt[dst[j] >> 8], 1);
    __syncthreads();
    for (int t = threadIdx.x; t < MAXNB; t += 256) {
        int c = cnt[t];
        if (c) wb[t] = atomicAdd(&gcursor[t], c);
    }
    __syncthreads();
    for (int j = lo + threadIdx.x; j < hi; j += 256) {
        int d = dst[j], s = src[j];
        int pos = atomicAdd(&wb[d >> 8], 1);
        bedge[pos] = ((d & (BKT - 1)) << 20) | s;
    }
}

// per-bucket in-LDS counting sort -> dst-sorted src list (in place), row_ptr, dinv
__global__ __launch_bounds__(256) void kB(int* __restrict__ bedge,
                                          const int* __restrict__ gbase,
                                          int* __restrict__ row_ptr,
                                          int* __restrict__ oflow,
                                          float* __restrict__ dinv, int n) {
    __shared__ int stage[STAGE_MAX];
    __shared__ int hist[BKT];
    __shared__ int cur[BKT];
    __shared__ int wsum[4];
    const int tid = threadIdx.x, b = blockIdx.x;
    const int lo = gbase[b], hi = gbase[b + 1], cnt = hi - lo;
    hist[tid] = 0;
    __syncthreads();
    const bool staged = (cnt <= STAGE_MAX);
    if (staged) {
        for (int j = tid; j < cnt; j += 256) {
            int w = bedge[lo + j];
            stage[j] = w;
            atomicAdd(&hist[((unsigned)w) >> 20], 1);
        }
    } else {
        for (int j = tid; j < cnt; j += 256)
            atomicAdd(&hist[((unsigned)bedge[lo + j]) >> 20], 1);
    }
    if (tid == 0) oflow[b] = staged ? 0 : 1;
    __syncthreads();
    int v = hist[tid];
    int sv = v;
#pragma unroll
    for (int off = 1; off < 64; off <<= 1) {
        int t = __shfl_up(sv, off, 64);
        if ((tid & 63) >= off) sv += t;
    }
    if ((tid & 63) == 63) wsum[tid >> 6] = sv;
    __syncthreads();
    int wo = 0;
    for (int w = 0; w < (tid >> 6); ++w) wo += wsum[w];
    int excl = wo + sv - v;
    cur[tid] = excl;
    int node = (b << 8) + tid;
    if (node < n) {
        row_ptr[node] = lo + excl;
        dinv[node] = rsqrtf(1.0f + (float)v);
    }
    __syncthreads();
    if (staged) {
        for (int j = tid; j < cnt; j += 256) {
            int w = stage[j];
            int pos = atomicAdd(&cur[((unsigned)w) >> 20], 1);
            bedge[lo + pos] = w & 1048575;
        }
    }
}

// layer-1: 4-lane-per-node register-accumulating gather + split MLP -> ts
__global__ __launch_bounds__(256) void kAgg(const int* __restrict__ bedge,
                                            const int* __restrict__ row_ptr,
                                            const int* __restrict__ gbase,
                                            const int* __restrict__ oflow,
                                            const float* __restrict__ x,
                                            const float* __restrict__ dinv,
                                            const float* __restrict__ W1,
                                            const float* __restrict__ b1,
                                            const float* __restrict__ W2,
                                            float* __restrict__ ts, int n) {
    __shared__ float W1s[F_IN * F_HID];
    __shared__ float b1s[F_HID];
    __shared__ float W2s[F_HID * F_OUT];
    for (int t = threadIdx.x; t < F_IN * F_HID; t += 256) W1s[t] = W1[t];
    if (threadIdx.x < F_HID) b1s[threadIdx.x] = b1[threadIdx.x];
    if (threadIdx.x < F_HID * F_OUT) W2s[threadIdx.x] = W2[threadIdx.x];
    __syncthreads();
    const int node = (blockIdx.x * 256 + threadIdx.x) / G;
    const int g = threadIdx.x & (G - 1);
    if (node >= n) return;
    const float dv = dinv[node];
    float acc[F_IN];
#pragma unroll
    for (int k = 0; k < F_IN; ++k) acc[k] = 0.0f;
    const int b = node >> 8;
    if (!oflow[b]) {
        int jb = row_ptr[node], je = row_ptr[node + 1];
        for (int j = jb + g; j < je; j += G) {
            int s = bedge[j];
            float w = dinv[s];
            const float4* xr = (const float4*)(x + (size_t)s * F_IN);
#pragma unroll
            for (int k = 0; k < 5; ++k) {
                float4 vv = xr[k];
                acc[k * 4 + 0] = fmaf(vv.x, w, acc[k * 4 + 0]);
                acc[k * 4 + 1] = fmaf(vv.y, w, acc[k * 4 + 1]);
                acc[k * 4 + 2] = fmaf(vv.z, w, acc[k * 4 + 2]);
                acc[k * 4 + 3] = fmaf(vv.w, w, acc[k * 4 + 3]);
            }
        }
    } else {  // unsorted flagged bucket: scan whole bucket, filter on dl
        int jb = gbase[b], je = gbase[b + 1];
        int dl = node & (BKT - 1);
        for (int j = jb + g; j < je; j += G) {
            unsigned w = (unsigned)bedge[j];
            if ((int)(w >> 20) == dl) {
                int s = (int)(w & 1048575u);
                float ww = dinv[s];
                const float4* xr = (const float4*)(x + (size_t)s * F_IN);
#pragma unroll
                for (int k = 0; k < 5; ++k) {
                    float4 vv = xr[k];
                    acc[k * 4 + 0] = fmaf(vv.x, ww, acc[k * 4 + 0]);
                    acc[k * 4 + 1] = fmaf(vv.y, ww, acc[k * 4 + 1]);
                    acc[k * 4 + 2] = fmaf(vv.z, ww, acc[k * 4 + 2]);
                    acc[k * 4 + 3] = fmaf(vv.w, ww, acc[k * 4 + 3]);
                }
            }
        }
    }
    if (g == 0) {  // self-loop term: x[node]*dv
        const float4* xr = (const float4*)(x + (size_t)node * F_IN);
#pragma unroll
        for (int k = 0; k < 5; ++k) {
            float4 vv = xr[k];
            acc[k * 4 + 0] = fmaf(vv.x, dv, acc[k * 4 + 0]);
            acc[k * 4 + 1] = fmaf(vv.y, dv, acc[k * 4 + 1]);
            acc[k * 4 + 2] = fmaf(vv.z, dv, acc[k * 4 + 2]);
            acc[k * 4 + 3] = fmaf(vv.w, dv, acc[k * 4 + 3]);
        }
    }
#pragma unroll
    for (int k = 0; k < F_IN; ++k) {  // butterfly: all 4 lanes get full sum; scale by dv
        acc[k] += __shfl_xor(acc[k], 1, 64);
        acc[k] += __shfl_xor(acc[k], 2, 64);
        acc[k] *= dv;
    }
    float t0 = 0.0f, t1 = 0.0f;  // lane g computes hidden units [g*16, g*16+16)
#pragma unroll
    for (int jj = 0; jj < 16; ++jj) {
        int j = g * 16 + jj;
        float a = b1s[j];
#pragma unroll
        for (int k = 0; k < F_IN; ++k) a = fmaf(acc[k], W1s[k * F_HID + j], a);
        float h = fmaxf(a, 0.0f);
        t0 = fmaf(h, W2s[j * F_OUT + 0], t0);
        t1 = fmaf(h, W2s[j * F_OUT + 1], t1);
    }
    t0 += __shfl_xor(t0, 1, 64); t0 += __shfl_xor(t0, 2, 64);
    t1 += __shfl_xor(t1, 1, 64); t1 += __shfl_xor(t1, 2, 64);
    if (g == 0) *(float2*)(ts + (size_t)node * 2) = make_float2(t0 * dv, t1 * dv);
}

// layer-2: 4-lane-per-node gather of ts -> out
__global__ __launch_bounds__(256) void kL2g(const int* __restrict__ bedge,
                                            const int* __restrict__ row_ptr,
                                            const int* __restrict__ gbase,
                                            const int* __restrict__ oflow,
                                            const float* __restrict__ ts,
                                            const float* __restrict__ dinv,
                                            const float* __restrict__ b2,
                                            float* __restrict__ out, int n) {
    const int node = (blockIdx.x * 256 + threadIdx.x) / G;
    const int g = threadIdx.x & (G - 1);
    if (node >= n) return;
    float a0 = 0.0f, a1 = 0.0f;
    const int b = node >> 8;
    if (!oflow[b]) {
        int jb = row_ptr[node], je = row_ptr[node + 1];
        for (int j = jb + g; j < je; j += G) {
            int s = bedge[j];
            float2 t = *(const float2*)(ts + (size_t)s * 2);
            a0 += t.x; a1 += t.y;
        }
    } else {
        int jb = gbase[b], je = gbase[b + 1];
        int dl = node & (BKT - 1);
        for (int j = jb + g; j < je; j += G) {
            unsigned w = (unsigned)bedge[j];
            if ((int)(w >> 20) == dl) {
                int s = (int)(w & 1048575u);
                float2 t = *(const float2*)(ts + (size_t)s * 2);
                a0 += t.x; a1 += t.y;
            }
        }
    }
    a0 += __shfl_xor(a0, 1, 64); a0 += __shfl_xor(a0, 2, 64);
    a1 += __shfl_xor(a1, 1, 64); a1 += __shfl_xor(a1, 2, 64);
    if (g == 0) {
        float dv = dinv[node];
        float2 t = *(const float2*)(ts + (size_t)node * 2);
        *(float2*)(out + (size_t)node * 2) =
            make_float2(b2[0] + (a0 + t.x) * dv, b2[1] + (a1 + t.y) * dv);
    }
}

// ===================== fallback: round-2 CSR path =====================

__global__ void k_zero_i(int* __restrict__ p, int n) {
    int i = blockIdx.x * blockDim.x + threadIdx.x;
    if (i < n) p[i] = 0;
}
__global__ void k_hist(const int* __restrict__ dst, int* __restrict__ counts, int e) {
    int i = blockIdx.x * blockDim.x + threadIdx.x;
    if (i < e) atomicAdd(&counts[dst[i]], 1);
}
__global__ __launch_bounds__(1024) void k_scan(const int* __restrict__ counts,
                                               int* __restrict__ row_ptr,
                                               int* __restrict__ cursor, int n) {
    __shared__ int warp_sums[16];
    __shared__ int carry_s;
    const int tid = threadIdx.x;
    const int lane = tid & 63, wid = tid >> 6;
    if (tid == 0) carry_s = 0;
    __syncthreads();
    for (int base = 0; base < n; base += 1024) {
        int i = base + tid;
        int v = (i < n) ? counts[i] : 0;
        int sv = v;
#pragma unroll
        for (int off = 1; off < 64; off <<= 1) {
            int t = __shfl_up(sv, off, 64);
            if (lane >= off) sv += t;
        }
        if (lane == 63) warp_sums[wid] = sv;
        __syncthreads();
        if (wid == 0 && lane < 16) {
            int ws = warp_sums[lane];
#pragma unroll
            for (int off = 1; off < 16; off <<= 1) {
                int t = __shfl_up(ws, off, 16);
                if (lane >= off) ws += t;
            }
            warp_sums[lane] = ws;
        }
        __syncthreads();
        int wofs = (wid > 0) ? warp_sums[wid - 1] : 0;
        int excl = carry_s + wofs + sv - v;
        if (i < n) { row_ptr[i] = excl; cursor[i] = excl; }
        __syncthreads();
        if (tid == 0) carry_s += warp_sums[15];
        __syncthreads();
    }
    if (tid == 0) row_ptr[n] = carry_s;
}
__global__ void k_fill(const int* __restrict__ src, const int* __restrict__ dst,
                       int* __restrict__ cursor, int* __restrict__ edge_src, int e) {
    int i = blockIdx.x * blockDim.x + threadIdx.x;
    if (i >= e) return;
    int s = src[i], d = dst[i];
    int pos = atomicAdd(&cursor[d], 1);
    edge_src[pos] = s;
}
__global__ void k_dinv_fb(const int* __restrict__ counts, float* __restrict__ dinv, int n) {
    int i = blockIdx.x * blockDim.x + threadIdx.x;
    if (i < n) dinv[i] = rsqrtf(1.0f + (float)counts[i]);
}
__global__ void k_gather_mlp(const int* __restrict__ row_ptr, const int* __restrict__ edge_src,
                             const float* __restrict__ x, const float* __restrict__ dinv,
                             const float* __restrict__ W1, const float* __restrict__ b1,
                             const float* __restrict__ W2, float* __restrict__ ts, int n) {
    __shared__ float W1s[F_IN * F_HID];
    __shared__ float b1s[F_HID];
    __shared__ float W2s[F_HID * F_OUT];
    for (int t = threadIdx.x; t < F_IN * F_HID; t += blockDim.x) W1s[t] = W1[t];
    if (threadIdx.x < F_HID) b1s[threadIdx.x] = b1[threadIdx.x];
    if (threadIdx.x < F_HID * F_OUT) W2s[threadIdx.x] = W2[threadIdx.x];
    __syncthreads();
    int i = blockIdx.x * blockDim.x + threadIdx.x;
    if (i >= n) return;
    float dv = dinv[i];
    float acc[F_IN];
    {
        float d2 = dv * dv;
        const float4* xr = (const float4*)(x + (size_t)i * F_IN);
#pragma unroll
        for (int k = 0; k < 5; ++k) {
            float4 v = xr[k];
            acc[k * 4 + 0] = v.x * d2; acc[k * 4 + 1] = v.y * d2;
            acc[k * 4 + 2] = v.z * d2; acc[k * 4 + 3] = v.w * d2;
        }
    }
    int jb = row_ptr[i], je = row_ptr[i + 1];
    for (int j = jb; j < je; ++j) {
        int s = edge_src[j];
        float w = dinv[s] * dv;
        const float4* xr = (const float4*)(x + (size_t)s * F_IN);
#pragma unroll
        for (int k = 0; k < 5; ++k) {
            float4 v = xr[k];
            acc[k * 4 + 0] = fmaf(v.x, w, acc[k * 4 + 0]);
            acc[k * 4 + 1] = fmaf(v.y, w, acc[k * 4 + 1]);
            acc[k * 4 + 2] = fmaf(v.z, w, acc[k * 4 + 2]);
            acc[k * 4 + 3] = fmaf(v.w, w, acc[k * 4 + 3]);
        }
    }
    float t0 = 0.0f, t1 = 0.0f;
#pragma unroll 8
    for (int j = 0; j < F_HID; ++j) {
        float a = b1s[j];
#pragma unroll
        for (int k = 0; k < F_IN; ++k) a = fmaf(acc[k], W1s[k * F_HID + j], a);
        float h = fmaxf(a, 0.0f);
        t0 = fmaf(h, W2s[j * F_OUT + 0], t0);
        t1 = fmaf(h, W2s[j * F_OUT + 1], t1);
    }
    ts[(size_t)i * 2 + 0] = t0 * dv;
    ts[(size_t)i * 2 + 1] = t1 * dv;
}
__global__ void k_gather2(const int* __restrict__ row_ptr, const int* __restrict__ edge_src,
                          const float* __restrict__ ts, const float* __restrict__ dinv,
                          const float* __restrict__ b2, float* __restrict__ out, int n) {
    int i = blockIdx.x * blockDim.x + threadIdx.x;
    if (i >= n) return;
    float dv = dinv[i];
    float2 t = *(const float2*)(ts + (size_t)i * 2);
    float a0 = t.x, a1 = t.y;
    int jb = row_ptr[i], je = row_ptr[i + 1];
    for (int j = jb; j < je; ++j) {
        int s = edge_src[j];
        float2 v = *(const float2*)(ts + (size_t)s * 2);
        a0 += v.x; a1 += v.y;
    }
    out[(size_t)i * 2 + 0] = b2[0] + a0 * dv;
    out[(size_t)i * 2 + 1] = b2[1] + a1 * dv;
}

// ============================ launch ============================

extern "C" void kernel_launch(void* const* d_in, const int* in_sizes, int n_in,
                              void* d_out, int out_size, void* d_ws, size_t ws_size,
                              hipStream_t stream) {
    const float* x  = (const float*)d_in[0];
    const int*   ei = (const int*)d_in[1];
    const float* W1 = (const float*)d_in[2];
    const float* b1 = (const float*)d_in[3];
    const float* W2 = (const float*)d_in[4];
    const float* b2 = (const float*)d_in[5];
    float* out = (float*)d_out;

    const int n = in_sizes[0] / F_IN;
    const int e = in_sizes[1] / 2;
    const int* src = ei;
    const int* dst = ei + e;

    const int B = 256;
    const int gn = (n + B - 1) / B;
    const int ge = (e + B - 1) / B;

    const int NB = (n + BKT - 1) / BKT;
    size_t need_b = ((size_t)NB * 3 + 1 + (size_t)e + (size_t)(n + 1) + 3 * (size_t)n) * 4;

    if (n < (1 << 20) && NB <= MAXNB && ws_size >= need_b) {
        int*   gcount  = (int*)d_ws;            // NB
        int*   gbase   = gcount + NB;           // NB+1
        int*   gcursor = gbase + NB + 1;        // NB (reused as oflow by kB)
        int*   bedge   = gcursor + NB;          // e
        int*   row_ptr = bedge + e;             // n+1
        float* dinv    = (float*)(row_ptr + n + 1); // n
        float* ts      = dinv + n;              // 2n
        int*   oflow   = gcursor;               // reuse after kA

        kz<<<(NB + 255) / 256, 256, 0, stream>>>(gcount, NB);
        kA0<<<NWG_A, 256, 0, stream>>>(dst, gcount, e);
        kscan<<<1, 64, 0, stream>>>(gcount, gbase, gcursor, row_ptr, NB, n);
        kA<<<NWG_A, 256, 0, stream>>>(src, dst, gcursor, bedge, e);
        kB<<<NB, 256, 0, stream>>>(bedge, gbase, row_ptr, oflow, dinv, n);
        int gg = ((size_t)n * G + 255) / 256;
        kAgg<<<gg, 256, 0, stream>>>(bedge, row_ptr, gbase, oflow, x, dinv, W1, b1, W2, ts, n);
        kL2g<<<gg, 256, 0, stream>>>(bedge, row_ptr, gbase, oflow, ts, dinv, b2, out, n);
    } else {
        int*   counts   = (int*)d_ws;
        int*   row_ptr  = counts + n;
        int*   cursor   = row_ptr + n + 1;
        int*   edge_src = cursor + n;
        float* dinv     = (float*)(edge_src + e);
        float* ts       = dinv + n;

        k_zero_i<<<gn, B, 0, stream>>>(counts, n);
        k_hist<<<ge, B, 0, stream>>>(dst, counts, e);
        k_scan<<<1, 1024, 0, stream>>>(counts, row_ptr, cursor, n);
        k_fill<<<ge, B, 0, stream>>>(src, dst, cursor, edge_src, e);
        k_dinv_fb<<<gn, B, 0, stream>>>(counts, dinv, n);
        k_gather_mlp<<<gn, B, 0, stream>>>(row_ptr, edge_src, x, dinv, W1, b1, W2, ts, n);
        k_gather2<<<gn, B, 0, stream>>>(row_ptr, edge_src, ts, dinv, b2, out, n);
    }
}

// Round 5
// 216.311 us; speedup vs baseline: 17.4725x; 1.0135x over previous
//
#include <hip/hip_runtime.h>
#include <hip/hip_fp16.h>

#define F_IN 20
#define F_HID 64
#define F_OUT 2
#define BKT 256        // nodes per bucket
#define MAXNB 512      // max buckets the LDS arrays support
#define NWG_A 512      // scatter workgroups
#define STAGE_MAX 14336 // per-bucket LDS edge staging capacity (56 KB)
#define G 4            // lanes per node in gather kernels

// ===================== bucketed + sorted path =====================

__global__ void kz(int* __restrict__ g, int nb) {
    int i = blockIdx.x * blockDim.x + threadIdx.x;
    if (i < nb) g[i] = 0;
}

// coarse histogram of dst>>8 (LDS-aggregated, then tiny global merge)
__global__ __launch_bounds__(256) void kA0(const int* __restrict__ dst,
                                           int* __restrict__ gcount, int e) {
    __shared__ int c[MAXNB];
    for (int t = threadIdx.x; t < MAXNB; t += 256) c[t] = 0;
    __syncthreads();
    int stride = gridDim.x * blockDim.x;
    for (int i = blockIdx.x * blockDim.x + threadIdx.x; i < e; i += stride)
        atomicAdd(&c[dst[i] >> 8], 1);
    __syncthreads();
    for (int t = threadIdx.x; t < MAXNB; t += 256)
        if (c[t]) atomicAdd(&gcount[t], c[t]);
}

__global__ void kscan(const int* __restrict__ gcount, int* __restrict__ gbase,
                      int* __restrict__ gcursor, int* __restrict__ row_ptr,
                      int nb, int n) {
    if (threadIdx.x == 0) {
        int acc = 0;
        for (int b = 0; b < nb; ++b) { gbase[b] = acc; gcursor[b] = acc; acc += gcount[b]; }
        gbase[nb] = acc;
        row_ptr[n] = acc;
    }
}

// scatter edges into coarse buckets as packed words: (dst&255)<<20 | src
__global__ __launch_bounds__(256) void kA(const int* __restrict__ src, const int* __restrict__ dst,
                                          int* __restrict__ gcursor, int* __restrict__ bedge, int e) {
    __shared__ int cnt[MAXNB];
    __shared__ int wb[MAXNB];
    int per = (e + gridDim.x - 1) / gridDim.x;
    int lo = blockIdx.x * per, hi = min(e, lo + per);
    for (int t = threadIdx.x; t < MAXNB; t += 256) cnt[t] = 0;
    __syncthreads();
    for (int j = lo + threadIdx.x; j < hi; j += 256) atomicAdd(&cnt[dst[j] >> 8], 1);
    __syncthreads();
    for (int t = threadIdx.x; t < MAXNB; t += 256) {
        int c = cnt[t];
        if (c) wb[t] = atomicAdd(&gcursor[t], c);
    }
    __syncthreads();
    for (int j = lo + threadIdx.x; j < hi; j += 256) {
        int d = dst[j], s = src[j];
        int pos = atomicAdd(&wb[d >> 8], 1);
        bedge[pos] = ((d & (BKT - 1)) << 20) | s;
    }
}

// per-bucket in-LDS counting sort -> dst-sorted src list (in place), row_ptr, dinv
__global__ __launch_bounds__(256) void kB(int* __restrict__ bedge,
                                          const int* __restrict__ gbase,
                                          int* __restrict__ row_ptr,
                                          int* __restrict__ oflow,
                                          float* __restrict__ dinv, int n) {
    __shared__ int stage[STAGE_MAX];
    __shared__ int hist[BKT];
    __shared__ int cur[BKT];
    __shared__ int wsum[4];
    const int tid = threadIdx.x, b = blockIdx.x;
    const int lo = gbase[b], hi = gbase[b + 1], cnt = hi - lo;
    hist[tid] = 0;
    __syncthreads();
    const bool staged = (cnt <= STAGE_MAX);
    if (staged) {
        for (int j = tid; j < cnt; j += 256) {
            int w = bedge[lo + j];
            stage[j] = w;
            atomicAdd(&hist[((unsigned)w) >> 20], 1);
        }
    } else {
        for (int j = tid; j < cnt; j += 256)
            atomicAdd(&hist[((unsigned)bedge[lo + j]) >> 20], 1);
    }
    if (tid == 0) oflow[b] = staged ? 0 : 1;
    __syncthreads();
    int v = hist[tid];
    int sv = v;
#pragma unroll
    for (int off = 1; off < 64; off <<= 1) {
        int t = __shfl_up(sv, off, 64);
        if ((tid & 63) >= off) sv += t;
    }
    if ((tid & 63) == 63) wsum[tid >> 6] = sv;
    __syncthreads();
    int wo = 0;
    for (int w = 0; w < (tid >> 6); ++w) wo += wsum[w];
    int excl = wo + sv - v;
    cur[tid] = excl;
    int node = (b << 8) + tid;
    if (node < n) {
        row_ptr[node] = lo + excl;
        dinv[node] = rsqrtf(1.0f + (float)v);
    }
    __syncthreads();
    if (staged) {
        for (int j = tid; j < cnt; j += 256) {
            int w = stage[j];
            int pos = atomicAdd(&cur[((unsigned)w) >> 20], 1);
            bedge[lo + pos] = w & 1048575;
        }
    }
}

// xh[i] = fp16(x[i] * dinv[i]), packed 40B/row (10 uints)
__global__ __launch_bounds__(256) void kxh(const float* __restrict__ x,
                                           const float* __restrict__ dinv,
                                           unsigned* __restrict__ xh, int n) {
    int i = blockIdx.x * blockDim.x + threadIdx.x;
    if (i >= n) return;
    float dv = dinv[i];
    const float4* xr = (const float4*)(x + (size_t)i * F_IN);
    uint2* xo = (uint2*)(xh + (size_t)i * 10);
#pragma unroll
    for (int k = 0; k < 5; ++k) {
        float4 v = xr[k];
        __half2 h0 = __float22half2_rn(make_float2(v.x * dv, v.y * dv));
        __half2 h1 = __float22half2_rn(make_float2(v.z * dv, v.w * dv));
        uint2 u;
        u.x = *(const unsigned*)&h0;
        u.y = *(const unsigned*)&h1;
        xo[k] = u;
    }
}

// layer-1 (fp16 table): 4-lane-per-node gather of xh + split MLP -> ts
__global__ __launch_bounds__(256) void kAgg_h(const int* __restrict__ bedge,
                                              const int* __restrict__ row_ptr,
                                              const int* __restrict__ gbase,
                                              const int* __restrict__ oflow,
                                              const float* __restrict__ x,
                                              const unsigned* __restrict__ xh,
                                              const float* __restrict__ dinv,
                                              const float* __restrict__ W1,
                                              const float* __restrict__ b1,
                                              const float* __restrict__ W2,
                                              float* __restrict__ ts, int n) {
    __shared__ float W1s[F_IN * F_HID];
    __shared__ float b1s[F_HID];
    __shared__ float W2s[F_HID * F_OUT];
    for (int t = threadIdx.x; t < F_IN * F_HID; t += 256) W1s[t] = W1[t];
    if (threadIdx.x < F_HID) b1s[threadIdx.x] = b1[threadIdx.x];
    if (threadIdx.x < F_HID * F_OUT) W2s[threadIdx.x] = W2[threadIdx.x];
    __syncthreads();
    const int node = (blockIdx.x * 256 + threadIdx.x) / G;
    const int g = threadIdx.x & (G - 1);
    if (node >= n) return;
    const float dv = dinv[node];
    float acc[F_IN];
#pragma unroll
    for (int k = 0; k < F_IN; ++k) acc[k] = 0.0f;
    const int b = node >> 8;
    if (!oflow[b]) {
        int jb = row_ptr[node], je = row_ptr[node + 1];
        for (int j = jb + g; j < je; j += G) {
            int s = __builtin_nontemporal_load(&bedge[j]);
            const uint2* xr = (const uint2*)(xh + (size_t)s * 10);
#pragma unroll
            for (int k = 0; k < 5; ++k) {
                uint2 u = xr[k];
                float2 f0 = __half22float2(*(const __half2*)&u.x);
                float2 f1 = __half22float2(*(const __half2*)&u.y);
                acc[k * 4 + 0] += f0.x;
                acc[k * 4 + 1] += f0.y;
                acc[k * 4 + 2] += f1.x;
                acc[k * 4 + 3] += f1.y;
            }
        }
    } else {  // unsorted flagged bucket: scan whole bucket, filter on dl
        int jb = gbase[b], je = gbase[b + 1];
        int dl = node & (BKT - 1);
        for (int j = jb + g; j < je; j += G) {
            unsigned w = (unsigned)__builtin_nontemporal_load(&bedge[j]);
            if ((int)(w >> 20) == dl) {
                int s = (int)(w & 1048575u);
                const uint2* xr = (const uint2*)(xh + (size_t)s * 10);
#pragma unroll
                for (int k = 0; k < 5; ++k) {
                    uint2 u = xr[k];
                    float2 f0 = __half22float2(*(const __half2*)&u.x);
                    float2 f1 = __half22float2(*(const __half2*)&u.y);
                    acc[k * 4 + 0] += f0.x;
                    acc[k * 4 + 1] += f0.y;
                    acc[k * 4 + 2] += f1.x;
                    acc[k * 4 + 3] += f1.y;
                }
            }
        }
    }
    if (g == 0) {  // self-loop term exact fp32: x[node]*dv
        const float4* xr = (const float4*)(x + (size_t)node * F_IN);
#pragma unroll
        for (int k = 0; k < 5; ++k) {
            float4 vv = xr[k];
            acc[k * 4 + 0] = fmaf(vv.x, dv, acc[k * 4 + 0]);
            acc[k * 4 + 1] = fmaf(vv.y, dv, acc[k * 4 + 1]);
            acc[k * 4 + 2] = fmaf(vv.z, dv, acc[k * 4 + 2]);
            acc[k * 4 + 3] = fmaf(vv.w, dv, acc[k * 4 + 3]);
        }
    }
#pragma unroll
    for (int k = 0; k < F_IN; ++k) {
        acc[k] += __shfl_xor(acc[k], 1, 64);
        acc[k] += __shfl_xor(acc[k], 2, 64);
        acc[k] *= dv;
    }
    float t0 = 0.0f, t1 = 0.0f;
#pragma unroll
    for (int jj = 0; jj < 16; ++jj) {
        int j = g * 16 + jj;
        float a = b1s[j];
#pragma unroll
        for (int k = 0; k < F_IN; ++k) a = fmaf(acc[k], W1s[k * F_HID + j], a);
        float h = fmaxf(a, 0.0f);
        t0 = fmaf(h, W2s[j * F_OUT + 0], t0);
        t1 = fmaf(h, W2s[j * F_OUT + 1], t1);
    }
    t0 += __shfl_xor(t0, 1, 64); t0 += __shfl_xor(t0, 2, 64);
    t1 += __shfl_xor(t1, 1, 64); t1 += __shfl_xor(t1, 2, 64);
    if (g == 0) *(float2*)(ts + (size_t)node * 2) = make_float2(t0 * dv, t1 * dv);
}

// layer-1 fp32 fallback (round-4 kAgg)
__global__ __launch_bounds__(256) void kAgg(const int* __restrict__ bedge,
                                            const int* __restrict__ row_ptr,
                                            const int* __restrict__ gbase,
                                            const int* __restrict__ oflow,
                                            const float* __restrict__ x,
                                            const float* __restrict__ dinv,
                                            const float* __restrict__ W1,
                                            const float* __restrict__ b1,
                                            const float* __restrict__ W2,
                                            float* __restrict__ ts, int n) {
    __shared__ float W1s[F_IN * F_HID];
    __shared__ float b1s[F_HID];
    __shared__ float W2s[F_HID * F_OUT];
    for (int t = threadIdx.x; t < F_IN * F_HID; t += 256) W1s[t] = W1[t];
    if (threadIdx.x < F_HID) b1s[threadIdx.x] = b1[threadIdx.x];
    if (threadIdx.x < F_HID * F_OUT) W2s[threadIdx.x] = W2[threadIdx.x];
    __syncthreads();
    const int node = (blockIdx.x * 256 + threadIdx.x) / G;
    const int g = threadIdx.x & (G - 1);
    if (node >= n) return;
    const float dv = dinv[node];
    float acc[F_IN];
#pragma unroll
    for (int k = 0; k < F_IN; ++k) acc[k] = 0.0f;
    const int b = node >> 8;
    if (!oflow[b]) {
        int jb = row_ptr[node], je = row_ptr[node + 1];
        for (int j = jb + g; j < je; j += G) {
            int s = bedge[j];
            float w = dinv[s];
            const float4* xr = (const float4*)(x + (size_t)s * F_IN);
#pragma unroll
            for (int k = 0; k < 5; ++k) {
                float4 vv = xr[k];
                acc[k * 4 + 0] = fmaf(vv.x, w, acc[k * 4 + 0]);
                acc[k * 4 + 1] = fmaf(vv.y, w, acc[k * 4 + 1]);
                acc[k * 4 + 2] = fmaf(vv.z, w, acc[k * 4 + 2]);
                acc[k * 4 + 3] = fmaf(vv.w, w, acc[k * 4 + 3]);
            }
        }
    } else {
        int jb = gbase[b], je = gbase[b + 1];
        int dl = node & (BKT - 1);
        for (int j = jb + g; j < je; j += G) {
            unsigned w = (unsigned)bedge[j];
            if ((int)(w >> 20) == dl) {
                int s = (int)(w & 1048575u);
                float ww = dinv[s];
                const float4* xr = (const float4*)(x + (size_t)s * F_IN);
#pragma unroll
                for (int k = 0; k < 5; ++k) {
                    float4 vv = xr[k];
                    acc[k * 4 + 0] = fmaf(vv.x, ww, acc[k * 4 + 0]);
                    acc[k * 4 + 1] = fmaf(vv.y, ww, acc[k * 4 + 1]);
                    acc[k * 4 + 2] = fmaf(vv.z, ww, acc[k * 4 + 2]);
                    acc[k * 4 + 3] = fmaf(vv.w, ww, acc[k * 4 + 3]);
                }
            }
        }
    }
    if (g == 0) {
        const float4* xr = (const float4*)(x + (size_t)node * F_IN);
#pragma unroll
        for (int k = 0; k < 5; ++k) {
            float4 vv = xr[k];
            acc[k * 4 + 0] = fmaf(vv.x, dv, acc[k * 4 + 0]);
            acc[k * 4 + 1] = fmaf(vv.y, dv, acc[k * 4 + 1]);
            acc[k * 4 + 2] = fmaf(vv.z, dv, acc[k * 4 + 2]);
            acc[k * 4 + 3] = fmaf(vv.w, dv, acc[k * 4 + 3]);
        }
    }
#pragma unroll
    for (int k = 0; k < F_IN; ++k) {
        acc[k] += __shfl_xor(acc[k], 1, 64);
        acc[k] += __shfl_xor(acc[k], 2, 64);
        acc[k] *= dv;
    }
    float t0 = 0.0f, t1 = 0.0f;
#pragma unroll
    for (int jj = 0; jj < 16; ++jj) {
        int j = g * 16 + jj;
        float a = b1s[j];
#pragma unroll
        for (int k = 0; k < F_IN; ++k) a = fmaf(acc[k], W1s[k * F_HID + j], a);
        float h = fmaxf(a, 0.0f);
        t0 = fmaf(h, W2s[j * F_OUT + 0], t0);
        t1 = fmaf(h, W2s[j * F_OUT + 1], t1);
    }
    t0 += __shfl_xor(t0, 1, 64); t0 += __shfl_xor(t0, 2, 64);
    t1 += __shfl_xor(t1, 1, 64); t1 += __shfl_xor(t1, 2, 64);
    if (g == 0) *(float2*)(ts + (size_t)node * 2) = make_float2(t0 * dv, t1 * dv);
}

// layer-2: 4-lane-per-node gather of ts -> out
__global__ __launch_bounds__(256) void kL2g(const int* __restrict__ bedge,
                                            const int* __restrict__ row_ptr,
                                            const int* __restrict__ gbase,
                                            const int* __restrict__ oflow,
                                            const float* __restrict__ ts,
                                            const float* __restrict__ dinv,
                                            const float* __restrict__ b2,
                                            float* __restrict__ out, int n) {
    const int node = (blockIdx.x * 256 + threadIdx.x) / G;
    const int g = threadIdx.x & (G - 1);
    if (node >= n) return;
    float a0 = 0.0f, a1 = 0.0f;
    const int b = node >> 8;
    if (!oflow[b]) {
        int jb = row_ptr[node], je = row_ptr[node + 1];
        for (int j = jb + g; j < je; j += G) {
            int s = __builtin_nontemporal_load(&bedge[j]);
            float2 t = *(const float2*)(ts + (size_t)s * 2);
            a0 += t.x; a1 += t.y;
        }
    } else {
        int jb = gbase[b], je = gbase[b + 1];
        int dl = node & (BKT - 1);
        for (int j = jb + g; j < je; j += G) {
            unsigned w = (unsigned)__builtin_nontemporal_load(&bedge[j]);
            if ((int)(w >> 20) == dl) {
                int s = (int)(w & 1048575u);
                float2 t = *(const float2*)(ts + (size_t)s * 2);
                a0 += t.x; a1 += t.y;
            }
        }
    }
    a0 += __shfl_xor(a0, 1, 64); a0 += __shfl_xor(a0, 2, 64);
    a1 += __shfl_xor(a1, 1, 64); a1 += __shfl_xor(a1, 2, 64);
    if (g == 0) {
        float dv = dinv[node];
        float2 t = *(const float2*)(ts + (size_t)node * 2);
        *(float2*)(out + (size_t)node * 2) =
            make_float2(b2[0] + (a0 + t.x) * dv, b2[1] + (a1 + t.y) * dv);
    }
}

// ===================== fallback: round-2 CSR path =====================

__global__ void k_zero_i(int* __restrict__ p, int n) {
    int i = blockIdx.x * blockDim.x + threadIdx.x;
    if (i < n) p[i] = 0;
}
__global__ void k_hist(const int* __restrict__ dst, int* __restrict__ counts, int e) {
    int i = blockIdx.x * blockDim.x + threadIdx.x;
    if (i < e) atomicAdd(&counts[dst[i]], 1);
}
__global__ __launch_bounds__(1024) void k_scan(const int* __restrict__ counts,
                                               int* __restrict__ row_ptr,
                                               int* __restrict__ cursor, int n) {
    __shared__ int warp_sums[16];
    __shared__ int carry_s;
    const int tid = threadIdx.x;
    const int lane = tid & 63, wid = tid >> 6;
    if (tid == 0) carry_s = 0;
    __syncthreads();
    for (int base = 0; base < n; base += 1024) {
        int i = base + tid;
        int v = (i < n) ? counts[i] : 0;
        int sv = v;
#pragma unroll
        for (int off = 1; off < 64; off <<= 1) {
            int t = __shfl_up(sv, off, 64);
            if (lane >= off) sv += t;
        }
        if (lane == 63) warp_sums[wid] = sv;
        __syncthreads();
        if (wid == 0 && lane < 16) {
            int ws = warp_sums[lane];
#pragma unroll
            for (int off = 1; off < 16; off <<= 1) {
                int t = __shfl_up(ws, off, 16);
                if (lane >= off) ws += t;
            }
            warp_sums[lane] = ws;
        }
        __syncthreads();
        int wofs = (wid > 0) ? warp_sums[wid - 1] : 0;
        int excl = carry_s + wofs + sv - v;
        if (i < n) { row_ptr[i] = excl; cursor[i] = excl; }
        __syncthreads();
        if (tid == 0) carry_s += warp_sums[15];
        __syncthreads();
    }
    if (tid == 0) row_ptr[n] = carry_s;
}
__global__ void k_fill(const int* __restrict__ src, const int* __restrict__ dst,
                       int* __restrict__ cursor, int* __restrict__ edge_src, int e) {
    int i = blockIdx.x * blockDim.x + threadIdx.x;
    if (i >= e) return;
    int s = src[i], d = dst[i];
    int pos = atomicAdd(&cursor[d], 1);
    edge_src[pos] = s;
}
__global__ void k_dinv_fb(const int* __restrict__ counts, float* __restrict__ dinv, int n) {
    int i = blockIdx.x * blockDim.x + threadIdx.x;
    if (i < n) dinv[i] = rsqrtf(1.0f + (float)counts[i]);
}
__global__ void k_gather_mlp(const int* __restrict__ row_ptr, const int* __restrict__ edge_src,
                             const float* __restrict__ x, const float* __restrict__ dinv,
                             const float* __restrict__ W1, const float* __restrict__ b1,
                             const float* __restrict__ W2, float* __restrict__ ts, int n) {
    __shared__ float W1s[F_IN * F_HID];
    __shared__ float b1s[F_HID];
    __shared__ float W2s[F_HID * F_OUT];
    for (int t = threadIdx.x; t < F_IN * F_HID; t += blockDim.x) W1s[t] = W1[t];
    if (threadIdx.x < F_HID) b1s[threadIdx.x] = b1[threadIdx.x];
    if (threadIdx.x < F_HID * F_OUT) W2s[threadIdx.x] = W2[threadIdx.x];
    __syncthreads();
    int i = blockIdx.x * blockDim.x + threadIdx.x;
    if (i >= n) return;
    float dv = dinv[i];
    float acc[F_IN];
    {
        float d2 = dv * dv;
        const float4* xr = (const float4*)(x + (size_t)i * F_IN);
#pragma unroll
        for (int k = 0; k < 5; ++k) {
            float4 v = xr[k];
            acc[k * 4 + 0] = v.x * d2; acc[k * 4 + 1] = v.y * d2;
            acc[k * 4 + 2] = v.z * d2; acc[k * 4 + 3] = v.w * d2;
        }
    }
    int jb = row_ptr[i], je = row_ptr[i + 1];
    for (int j = jb; j < je; ++j) {
        int s = edge_src[j];
        float w = dinv[s] * dv;
        const float4* xr = (const float4*)(x + (size_t)s * F_IN);
#pragma unroll
        for (int k = 0; k < 5; ++k) {
            float4 v = xr[k];
            acc[k * 4 + 0] = fmaf(v.x, w, acc[k * 4 + 0]);
            acc[k * 4 + 1] = fmaf(v.y, w, acc[k * 4 + 1]);
            acc[k * 4 + 2] = fmaf(v.z, w, acc[k * 4 + 2]);
            acc[k * 4 + 3] = fmaf(v.w, w, acc[k * 4 + 3]);
        }
    }
    float t0 = 0.0f, t1 = 0.0f;
#pragma unroll 8
    for (int j = 0; j < F_HID; ++j) {
        float a = b1s[j];
#pragma unroll
        for (int k = 0; k < F_IN; ++k) a = fmaf(acc[k], W1s[k * F_HID + j], a);
        float h = fmaxf(a, 0.0f);
        t0 = fmaf(h, W2s[j * F_OUT + 0], t0);
        t1 = fmaf(h, W2s[j * F_OUT + 1], t1);
    }
    ts[(size_t)i * 2 + 0] = t0 * dv;
    ts[(size_t)i * 2 + 1] = t1 * dv;
}
__global__ void k_gather2(const int* __restrict__ row_ptr, const int* __restrict__ edge_src,
                          const float* __restrict__ ts, const float* __restrict__ dinv,
                          const float* __restrict__ b2, float* __restrict__ out, int n) {
    int i = blockIdx.x * blockDim.x + threadIdx.x;
    if (i >= n) return;
    float dv = dinv[i];
    float2 t = *(const float2*)(ts + (size_t)i * 2);
    float a0 = t.x, a1 = t.y;
    int jb = row_ptr[i], je = row_ptr[i + 1];
    for (int j = jb; j < je; ++j) {
        int s = edge_src[j];
        float2 v = *(const float2*)(ts + (size_t)s * 2);
        a0 += v.x; a1 += v.y;
    }
    out[(size_t)i * 2 + 0] = b2[0] + a0 * dv;
    out[(size_t)i * 2 + 1] = b2[1] + a1 * dv;
}

// ============================ launch ============================

extern "C" void kernel_launch(void* const* d_in, const int* in_sizes, int n_in,
                              void* d_out, int out_size, void* d_ws, size_t ws_size,
                              hipStream_t stream) {
    const float* x  = (const float*)d_in[0];
    const int*   ei = (const int*)d_in[1];
    const float* W1 = (const float*)d_in[2];
    const float* b1 = (const float*)d_in[3];
    const float* W2 = (const float*)d_in[4];
    const float* b2 = (const float*)d_in[5];
    float* out = (float*)d_out;

    const int n = in_sizes[0] / F_IN;
    const int e = in_sizes[1] / 2;
    const int* src = ei;
    const int* dst = ei + e;

    const int B = 256;
    const int gn = (n + B - 1) / B;
    const int ge = (e + B - 1) / B;

    const int NB = (n + BKT - 1) / BKT;
    size_t need_b = ((size_t)NB * 3 + 1 + (size_t)e + (size_t)(n + 1) + 3 * (size_t)n) * 4;
    size_t need_h = need_b + (size_t)n * 10 * 4;

    if (n < (1 << 20) && NB <= MAXNB && ws_size >= need_b) {
        int*   gcount  = (int*)d_ws;            // NB
        int*   gbase   = gcount + NB;           // NB+1
        int*   gcursor = gbase + NB + 1;        // NB (reused as oflow by kB)
        int*   bedge   = gcursor + NB;          // e
        int*   row_ptr = bedge + e;             // n+1
        float* dinv    = (float*)(row_ptr + n + 1); // n
        float* ts      = dinv + n;              // 2n
        unsigned* xh   = (unsigned*)(ts + 2 * (size_t)n); // 10n (fp16 path only)
        int*   oflow   = gcursor;               // reuse after kA

        kz<<<(NB + 255) / 256, 256, 0, stream>>>(gcount, NB);
        kA0<<<NWG_A, 256, 0, stream>>>(dst, gcount, e);
        kscan<<<1, 64, 0, stream>>>(gcount, gbase, gcursor, row_ptr, NB, n);
        kA<<<NWG_A, 256, 0, stream>>>(src, dst, gcursor, bedge, e);
        kB<<<NB, 256, 0, stream>>>(bedge, gbase, row_ptr, oflow, dinv, n);
        int gg = ((size_t)n * G + 255) / 256;
        if (ws_size >= need_h) {
            kxh<<<gn, B, 0, stream>>>(x, dinv, xh, n);
            kAgg_h<<<gg, 256, 0, stream>>>(bedge, row_ptr, gbase, oflow, x, xh, dinv,
                                           W1, b1, W2, ts, n);
        } else {
            kAgg<<<gg, 256, 0, stream>>>(bedge, row_ptr, gbase, oflow, x, dinv,
                                         W1, b1, W2, ts, n);
        }
        kL2g<<<gg, 256, 0, stream>>>(bedge, row_ptr, gbase, oflow, ts, dinv, b2, out, n);
    } else {
        int*   counts   = (int*)d_ws;
        int*   row_ptr  = counts + n;
        int*   cursor   = row_ptr + n + 1;
        int*   edge_src = cursor + n;
        float* dinv     = (float*)(edge_src + e);
        float* ts       = dinv + n;

        k_zero_i<<<gn, B, 0, stream>>>(counts, n);
        k_hist<<<ge, B, 0, stream>>>(dst, counts, e);
        k_scan<<<1, 1024, 0, stream>>>(counts, row_ptr, cursor, n);
        k_fill<<<ge, B, 0, stream>>>(src, dst, cursor, edge_src, e);
        k_dinv_fb<<<gn, B, 0, stream>>>(counts, dinv, n);
        k_gather_mlp<<<gn, B, 0, stream>>>(row_ptr, edge_src, x, dinv, W1, b1, W2, ts, n);
        k_gather2<<<gn, B, 0, stream>>>(row_ptr, edge_src, ts, dinv, b2, out, n);
    }
}

// Round 6
// 202.131 us; speedup vs baseline: 18.6983x; 1.0702x over previous
//
#include <hip/hip_runtime.h>
#include <hip/hip_fp16.h>

#define F_IN 20
#define F_HID 64
#define F_OUT 2
#define BKT 256        // nodes per bucket
#define MAXNB 512      // max buckets the LDS arrays support
#define NWG_A 512      // kA0 histogram workgroups
#define STAGE_MAX 14336 // per-bucket LDS edge staging capacity (56 KB)
#define G 4            // lanes per node (40B fallback + layer2)
#define G8 8           // lanes per node (64B path)
#define CHUNK 4096     // edges per WG in kA2

// ===================== bucketed + sorted path =====================

__global__ void kz(int* __restrict__ g, int nb) {
    int i = blockIdx.x * blockDim.x + threadIdx.x;
    if (i < nb) g[i] = 0;
}

// coarse histogram of dst>>8 (LDS-aggregated, then tiny global merge)
__global__ __launch_bounds__(256) void kA0(const int* __restrict__ dst,
                                           int* __restrict__ gcount, int e) {
    __shared__ int c[MAXNB];
    for (int t = threadIdx.x; t < MAXNB; t += 256) c[t] = 0;
    __syncthreads();
    int stride = gridDim.x * blockDim.x;
    for (int i = blockIdx.x * blockDim.x + threadIdx.x; i < e; i += stride)
        atomicAdd(&c[dst[i] >> 8], 1);
    __syncthreads();
    for (int t = threadIdx.x; t < MAXNB; t += 256)
        if (c[t]) atomicAdd(&gcount[t], c[t]);
}

// parallel exclusive scan over nb<=512 bins (one 256-thread WG, 2 bins/thread)
__global__ __launch_bounds__(256) void kscan_p(const int* __restrict__ gcount,
                                               int* __restrict__ gbase,
                                               int* __restrict__ gcursor,
                                               int* __restrict__ row_ptr,
                                               int nb, int n) {
    __shared__ int wtot[4];
    const int tid = threadIdx.x;
    const int t2 = tid * 2;
    int v0 = (t2 < nb) ? gcount[t2] : 0;
    int v1 = (t2 + 1 < nb) ? gcount[t2 + 1] : 0;
    int pv = v0 + v1;
    int sv = pv;
#pragma unroll
    for (int off = 1; off < 64; off <<= 1) {
        int u = __shfl_up(sv, off, 64);
        if ((tid & 63) >= off) sv += u;
    }
    if ((tid & 63) == 63) wtot[tid >> 6] = sv;
    __syncthreads();
    int wo = 0;
    for (int w = 0; w < (tid >> 6); ++w) wo += wtot[w];
    int excl = wo + sv - pv;
    if (t2 < nb)     { gbase[t2] = excl;          gcursor[t2] = excl; }
    if (t2 + 1 < nb) { gbase[t2 + 1] = excl + v0; gcursor[t2 + 1] = excl + v0; }
    if (tid == 0) {
        int total = wtot[0] + wtot[1] + wtot[2] + wtot[3];
        gbase[nb] = total;
        row_ptr[n] = total;
    }
}

// LDS-reorder scatter: chunk -> local counting sort by bucket -> coalesced run writes
__global__ __launch_bounds__(256) void kA2(const int* __restrict__ src,
                                           const int* __restrict__ dst,
                                           int* __restrict__ gcursor,
                                           int* __restrict__ bedge, int e, int nb) {
    __shared__ int stage[CHUNK];
    __shared__ unsigned short bkt[CHUNK];
    __shared__ unsigned short inv[CHUNK];
    __shared__ int cnt[MAXNB];
    __shared__ int lbase[MAXNB];
    __shared__ int lcur[MAXNB];
    __shared__ int gclaim[MAXNB];
    __shared__ int wtot[4];
    const int tid = threadIdx.x;
    const int lo = blockIdx.x * CHUNK;
    const int hi = min(e, lo + CHUNK);
    const int cn = hi - lo;
    for (int t = tid; t < MAXNB; t += 256) cnt[t] = 0;
    __syncthreads();
    for (int j = tid; j < cn; j += 256) {
        int d = dst[lo + j], s = src[lo + j];
        int b = d >> 8;
        stage[j] = ((d & (BKT - 1)) << 20) | s;
        bkt[j] = (unsigned short)b;
        atomicAdd(&cnt[b], 1);
    }
    __syncthreads();
    // block exclusive scan over 512 bins, 2 bins/thread
    const int t2 = tid * 2;
    int v0 = cnt[t2], v1 = cnt[t2 + 1];
    int pv = v0 + v1;
    int sv = pv;
#pragma unroll
    for (int off = 1; off < 64; off <<= 1) {
        int u = __shfl_up(sv, off, 64);
        if ((tid & 63) >= off) sv += u;
    }
    if ((tid & 63) == 63) wtot[tid >> 6] = sv;
    __syncthreads();
    int wo = 0;
    for (int w = 0; w < (tid >> 6); ++w) wo += wtot[w];
    int excl = wo + sv - pv;
    lbase[t2] = excl;          lcur[t2] = excl;
    lbase[t2 + 1] = excl + v0; lcur[t2 + 1] = excl + v0;
    if (v0 && t2 < nb)     gclaim[t2]     = atomicAdd(&gcursor[t2], v0);
    if (v1 && t2 + 1 < nb) gclaim[t2 + 1] = atomicAdd(&gcursor[t2 + 1], v1);
    __syncthreads();
    // local permutation: inv[sorted_pos] = arrival_idx
    for (int j = tid; j < cn; j += 256) {
        int p = atomicAdd(&lcur[bkt[j]], 1);
        inv[p] = (unsigned short)j;
    }
    __syncthreads();
    // coalesced run writes
    for (int t = tid; t < cn; t += 256) {
        int j = inv[t];
        int b = bkt[j];
        bedge[gclaim[b] + (t - lbase[b])] = stage[j];
    }
}

// per-bucket in-LDS counting sort -> dst-sorted src list (in place), row_ptr, dinv
__global__ __launch_bounds__(256) void kB(int* __restrict__ bedge,
                                          const int* __restrict__ gbase,
                                          int* __restrict__ row_ptr,
                                          int* __restrict__ oflow,
                                          float* __restrict__ dinv, int n) {
    __shared__ int stage[STAGE_MAX];
    __shared__ int hist[BKT];
    __shared__ int cur[BKT];
    __shared__ int wsum[4];
    const int tid = threadIdx.x, b = blockIdx.x;
    const int lo = gbase[b], hi = gbase[b + 1], cnt = hi - lo;
    hist[tid] = 0;
    __syncthreads();
    const bool staged = (cnt <= STAGE_MAX);
    if (staged) {
        for (int j = tid; j < cnt; j += 256) {
            int w = bedge[lo + j];
            stage[j] = w;
            atomicAdd(&hist[((unsigned)w) >> 20], 1);
        }
    } else {
        for (int j = tid; j < cnt; j += 256)
            atomicAdd(&hist[((unsigned)bedge[lo + j]) >> 20], 1);
    }
    if (tid == 0) oflow[b] = staged ? 0 : 1;
    __syncthreads();
    int v = hist[tid];
    int sv = v;
#pragma unroll
    for (int off = 1; off < 64; off <<= 1) {
        int t = __shfl_up(sv, off, 64);
        if ((tid & 63) >= off) sv += t;
    }
    if ((tid & 63) == 63) wsum[tid >> 6] = sv;
    __syncthreads();
    int wo = 0;
    for (int w = 0; w < (tid >> 6); ++w) wo += wsum[w];
    int excl = wo + sv - v;
    cur[tid] = excl;
    int node = (b << 8) + tid;
    if (node < n) {
        row_ptr[node] = lo + excl;
        dinv[node] = rsqrtf(1.0f + (float)v);
    }
    __syncthreads();
    if (staged) {
        for (int j = tid; j < cnt; j += 256) {
            int w = stage[j];
            int pos = atomicAdd(&cur[((unsigned)w) >> 20], 1);
            bedge[lo + pos] = w & 1048575;
        }
    }
}

// ---------- 64B-padded fp16 table path ----------

// xh64[i] = fp16(x[i]*dinv[i]) padded to 64B/row (4 x uint4)
__global__ __launch_bounds__(256) void kxh64(const float* __restrict__ x,
                                             const float* __restrict__ dinv,
                                             uint4* __restrict__ xh, int n) {
    int i = blockIdx.x * blockDim.x + threadIdx.x;
    if (i >= n) return;
    float dv = dinv[i];
    const float4* xr = (const float4*)(x + (size_t)i * F_IN);
    unsigned w[10];
#pragma unroll
    for (int k = 0; k < 5; ++k) {
        float4 v = xr[k];
        __half2 h0 = __float22half2_rn(make_float2(v.x * dv, v.y * dv));
        __half2 h1 = __float22half2_rn(make_float2(v.z * dv, v.w * dv));
        w[k * 2 + 0] = *(const unsigned*)&h0;
        w[k * 2 + 1] = *(const unsigned*)&h1;
    }
    uint4* o = xh + (size_t)i * 4;
    o[0] = make_uint4(w[0], w[1], w[2], w[3]);
    o[1] = make_uint4(w[4], w[5], w[6], w[7]);
    o[2] = make_uint4(w[8], w[9], 0u, 0u);
    o[3] = make_uint4(0u, 0u, 0u, 0u);
}

#define ACC2(u, idx) { float2 f_ = __half22float2(*(const __half2*)&(u)); \
                       acc[idx] += f_.x; acc[idx + 1] += f_.y; }

// layer-1 (64B fp16 table): 8-lane-per-node gather + split MLP -> ts
__global__ __launch_bounds__(256) void kAgg_h64(const int* __restrict__ bedge,
                                                const int* __restrict__ row_ptr,
                                                const int* __restrict__ gbase,
                                                const int* __restrict__ oflow,
                                                const float* __restrict__ x,
                                                const uint4* __restrict__ xh,
                                                const float* __restrict__ dinv,
                                                const float* __restrict__ W1,
                                                const float* __restrict__ b1,
                                                const float* __restrict__ W2,
                                                float* __restrict__ ts, int n) {
    __shared__ float W1s[F_IN * F_HID];
    __shared__ float b1s[F_HID];
    __shared__ float W2s[F_HID * F_OUT];
    for (int t = threadIdx.x; t < F_IN * F_HID; t += 256) W1s[t] = W1[t];
    if (threadIdx.x < F_HID) b1s[threadIdx.x] = b1[threadIdx.x];
    if (threadIdx.x < F_HID * F_OUT) W2s[threadIdx.x] = W2[threadIdx.x];
    __syncthreads();
    const int node = (blockIdx.x * 256 + threadIdx.x) >> 3;
    const int g = threadIdx.x & (G8 - 1);
    if (node >= n) return;
    const float dv = dinv[node];
    float acc[F_IN];
#pragma unroll
    for (int k = 0; k < F_IN; ++k) acc[k] = 0.0f;
    const int b = node >> 8;
    if (!oflow[b]) {
        int jb = row_ptr[node], je = row_ptr[node + 1];
        for (int j = jb + g; j < je; j += G8) {
            int s = __builtin_nontemporal_load(&bedge[j]);
            const uint4* r = xh + (size_t)s * 4;
            uint4 q0 = r[0], q1 = r[1], q2 = r[2];
            ACC2(q0.x, 0)  ACC2(q0.y, 2)  ACC2(q0.z, 4)  ACC2(q0.w, 6)
            ACC2(q1.x, 8)  ACC2(q1.y, 10) ACC2(q1.z, 12) ACC2(q1.w, 14)
            ACC2(q2.x, 16) ACC2(q2.y, 18)
        }
    } else {  // unsorted flagged bucket: scan whole bucket, filter on dl
        int jb = gbase[b], je = gbase[b + 1];
        int dl = node & (BKT - 1);
        for (int j = jb + g; j < je; j += G8) {
            unsigned w = (unsigned)__builtin_nontemporal_load(&bedge[j]);
            if ((int)(w >> 20) == dl) {
                int s = (int)(w & 1048575u);
                const uint4* r = xh + (size_t)s * 4;
                uint4 q0 = r[0], q1 = r[1], q2 = r[2];
                ACC2(q0.x, 0)  ACC2(q0.y, 2)  ACC2(q0.z, 4)  ACC2(q0.w, 6)
                ACC2(q1.x, 8)  ACC2(q1.y, 10) ACC2(q1.z, 12) ACC2(q1.w, 14)
                ACC2(q2.x, 16) ACC2(q2.y, 18)
            }
        }
    }
    if (g == 0) {  // self-loop term exact fp32: x[node]*dv
        const float4* xr = (const float4*)(x + (size_t)node * F_IN);
#pragma unroll
        for (int k = 0; k < 5; ++k) {
            float4 vv = xr[k];
            acc[k * 4 + 0] = fmaf(vv.x, dv, acc[k * 4 + 0]);
            acc[k * 4 + 1] = fmaf(vv.y, dv, acc[k * 4 + 1]);
            acc[k * 4 + 2] = fmaf(vv.z, dv, acc[k * 4 + 2]);
            acc[k * 4 + 3] = fmaf(vv.w, dv, acc[k * 4 + 3]);
        }
    }
#pragma unroll
    for (int k = 0; k < F_IN; ++k) {
        acc[k] += __shfl_xor(acc[k], 1, 64);
        acc[k] += __shfl_xor(acc[k], 2, 64);
        acc[k] += __shfl_xor(acc[k], 4, 64);
        acc[k] *= dv;
    }
    float t0 = 0.0f, t1 = 0.0f;  // lane g: hidden units [g*8, g*8+8)
#pragma unroll
    for (int jj = 0; jj < 8; ++jj) {
        int j = g * 8 + jj;
        float a = b1s[j];
#pragma unroll
        for (int k = 0; k < F_IN; ++k) a = fmaf(acc[k], W1s[k * F_HID + j], a);
        float h = fmaxf(a, 0.0f);
        t0 = fmaf(h, W2s[j * F_OUT + 0], t0);
        t1 = fmaf(h, W2s[j * F_OUT + 1], t1);
    }
    t0 += __shfl_xor(t0, 1, 64); t0 += __shfl_xor(t0, 2, 64); t0 += __shfl_xor(t0, 4, 64);
    t1 += __shfl_xor(t1, 1, 64); t1 += __shfl_xor(t1, 2, 64); t1 += __shfl_xor(t1, 4, 64);
    if (g == 0) *(float2*)(ts + (size_t)node * 2) = make_float2(t0 * dv, t1 * dv);
}

// ---------- 40B fp16 table path (round-5, fallback) ----------

__global__ __launch_bounds__(256) void kxh(const float* __restrict__ x,
                                           const float* __restrict__ dinv,
                                           unsigned* __restrict__ xh, int n) {
    int i = blockIdx.x * blockDim.x + threadIdx.x;
    if (i >= n) return;
    float dv = dinv[i];
    const float4* xr = (const float4*)(x + (size_t)i * F_IN);
    uint2* xo = (uint2*)(xh + (size_t)i * 10);
#pragma unroll
    for (int k = 0; k < 5; ++k) {
        float4 v = xr[k];
        __half2 h0 = __float22half2_rn(make_float2(v.x * dv, v.y * dv));
        __half2 h1 = __float22half2_rn(make_float2(v.z * dv, v.w * dv));
        uint2 u;
        u.x = *(const unsigned*)&h0;
        u.y = *(const unsigned*)&h1;
        xo[k] = u;
    }
}

__global__ __launch_bounds__(256) void kAgg_h(const int* __restrict__ bedge,
                                              const int* __restrict__ row_ptr,
                                              const int* __restrict__ gbase,
                                              const int* __restrict__ oflow,
                                              const float* __restrict__ x,
                                              const unsigned* __restrict__ xh,
                                              const float* __restrict__ dinv,
                                              const float* __restrict__ W1,
                                              const float* __restrict__ b1,
                                              const float* __restrict__ W2,
                                              float* __restrict__ ts, int n) {
    __shared__ float W1s[F_IN * F_HID];
    __shared__ float b1s[F_HID];
    __shared__ float W2s[F_HID * F_OUT];
    for (int t = threadIdx.x; t < F_IN * F_HID; t += 256) W1s[t] = W1[t];
    if (threadIdx.x < F_HID) b1s[threadIdx.x] = b1[threadIdx.x];
    if (threadIdx.x < F_HID * F_OUT) W2s[threadIdx.x] = W2[threadIdx.x];
    __syncthreads();
    const int node = (blockIdx.x * 256 + threadIdx.x) / G;
    const int g = threadIdx.x & (G - 1);
    if (node >= n) return;
    const float dv = dinv[node];
    float acc[F_IN];
#pragma unroll
    for (int k = 0; k < F_IN; ++k) acc[k] = 0.0f;
    const int b = node >> 8;
    if (!oflow[b]) {
        int jb = row_ptr[node], je = row_ptr[node + 1];
        for (int j = jb + g; j < je; j += G) {
            int s = __builtin_nontemporal_load(&bedge[j]);
            const uint2* xr = (const uint2*)(xh + (size_t)s * 10);
#pragma unroll
            for (int k = 0; k < 5; ++k) {
                uint2 u = xr[k];
                ACC2(u.x, k * 4)
                ACC2(u.y, k * 4 + 2)
            }
        }
    } else {
        int jb = gbase[b], je = gbase[b + 1];
        int dl = node & (BKT - 1);
        for (int j = jb + g; j < je; j += G) {
            unsigned w = (unsigned)__builtin_nontemporal_load(&bedge[j]);
            if ((int)(w >> 20) == dl) {
                int s = (int)(w & 1048575u);
                const uint2* xr = (const uint2*)(xh + (size_t)s * 10);
#pragma unroll
                for (int k = 0; k < 5; ++k) {
                    uint2 u = xr[k];
                    ACC2(u.x, k * 4)
                    ACC2(u.y, k * 4 + 2)
                }
            }
        }
    }
    if (g == 0) {
        const float4* xr = (const float4*)(x + (size_t)node * F_IN);
#pragma unroll
        for (int k = 0; k < 5; ++k) {
            float4 vv = xr[k];
            acc[k * 4 + 0] = fmaf(vv.x, dv, acc[k * 4 + 0]);
            acc[k * 4 + 1] = fmaf(vv.y, dv, acc[k * 4 + 1]);
            acc[k * 4 + 2] = fmaf(vv.z, dv, acc[k * 4 + 2]);
            acc[k * 4 + 3] = fmaf(vv.w, dv, acc[k * 4 + 3]);
        }
    }
#pragma unroll
    for (int k = 0; k < F_IN; ++k) {
        acc[k] += __shfl_xor(acc[k], 1, 64);
        acc[k] += __shfl_xor(acc[k], 2, 64);
        acc[k] *= dv;
    }
    float t0 = 0.0f, t1 = 0.0f;
#pragma unroll
    for (int jj = 0; jj < 16; ++jj) {
        int j = g * 16 + jj;
        float a = b1s[j];
#pragma unroll
        for (int k = 0; k < F_IN; ++k) a = fmaf(acc[k], W1s[k * F_HID + j], a);
        float h = fmaxf(a, 0.0f);
        t0 = fmaf(h, W2s[j * F_OUT + 0], t0);
        t1 = fmaf(h, W2s[j * F_OUT + 1], t1);
    }
    t0 += __shfl_xor(t0, 1, 64); t0 += __shfl_xor(t0, 2, 64);
    t1 += __shfl_xor(t1, 1, 64); t1 += __shfl_xor(t1, 2, 64);
    if (g == 0) *(float2*)(ts + (size_t)node * 2) = make_float2(t0 * dv, t1 * dv);
}

// layer-1 fp32 fallback
__global__ __launch_bounds__(256) void kAgg(const int* __restrict__ bedge,
                                            const int* __restrict__ row_ptr,
                                            const int* __restrict__ gbase,
                                            const int* __restrict__ oflow,
                                            const float* __restrict__ x,
                                            const float* __restrict__ dinv,
                                            const float* __restrict__ W1,
                                            const float* __restrict__ b1,
                                            const float* __restrict__ W2,
                                            float* __restrict__ ts, int n) {
    __shared__ float W1s[F_IN * F_HID];
    __shared__ float b1s[F_HID];
    __shared__ float W2s[F_HID * F_OUT];
    for (int t = threadIdx.x; t < F_IN * F_HID; t += 256) W1s[t] = W1[t];
    if (threadIdx.x < F_HID) b1s[threadIdx.x] = b1[threadIdx.x];
    if (threadIdx.x < F_HID * F_OUT) W2s[threadIdx.x] = W2[threadIdx.x];
    __syncthreads();
    const int node = (blockIdx.x * 256 + threadIdx.x) / G;
    const int g = threadIdx.x & (G - 1);
    if (node >= n) return;
    const float dv = dinv[node];
    float acc[F_IN];
#pragma unroll
    for (int k = 0; k < F_IN; ++k) acc[k] = 0.0f;
    const int b = node >> 8;
    if (!oflow[b]) {
        int jb = row_ptr[node], je = row_ptr[node + 1];
        for (int j = jb + g; j < je; j += G) {
            int s = bedge[j];
            float w = dinv[s];
            const float4* xr = (const float4*)(x + (size_t)s * F_IN);
#pragma unroll
            for (int k = 0; k < 5; ++k) {
                float4 vv = xr[k];
                acc[k * 4 + 0] = fmaf(vv.x, w, acc[k * 4 + 0]);
                acc[k * 4 + 1] = fmaf(vv.y, w, acc[k * 4 + 1]);
                acc[k * 4 + 2] = fmaf(vv.z, w, acc[k * 4 + 2]);
                acc[k * 4 + 3] = fmaf(vv.w, w, acc[k * 4 + 3]);
            }
        }
    } else {
        int jb = gbase[b], je = gbase[b + 1];
        int dl = node & (BKT - 1);
        for (int j = jb + g; j < je; j += G) {
            unsigned w = (unsigned)bedge[j];
            if ((int)(w >> 20) == dl) {
                int s = (int)(w & 1048575u);
                float ww = dinv[s];
                const float4* xr = (const float4*)(x + (size_t)s * F_IN);
#pragma unroll
                for (int k = 0; k < 5; ++k) {
                    float4 vv = xr[k];
                    acc[k * 4 + 0] = fmaf(vv.x, ww, acc[k * 4 + 0]);
                    acc[k * 4 + 1] = fmaf(vv.y, ww, acc[k * 4 + 1]);
                    acc[k * 4 + 2] = fmaf(vv.z, ww, acc[k * 4 + 2]);
                    acc[k * 4 + 3] = fmaf(vv.w, ww, acc[k * 4 + 3]);
                }
            }
        }
    }
    if (g == 0) {
        const float4* xr = (const float4*)(x + (size_t)node * F_IN);
#pragma unroll
        for (int k = 0; k < 5; ++k) {
            float4 vv = xr[k];
            acc[k * 4 + 0] = fmaf(vv.x, dv, acc[k * 4 + 0]);
            acc[k * 4 + 1] = fmaf(vv.y, dv, acc[k * 4 + 1]);
            acc[k * 4 + 2] = fmaf(vv.z, dv, acc[k * 4 + 2]);
            acc[k * 4 + 3] = fmaf(vv.w, dv, acc[k * 4 + 3]);
        }
    }
#pragma unroll
    for (int k = 0; k < F_IN; ++k) {
        acc[k] += __shfl_xor(acc[k], 1, 64);
        acc[k] += __shfl_xor(acc[k], 2, 64);
        acc[k] *= dv;
    }
    float t0 = 0.0f, t1 = 0.0f;
#pragma unroll
    for (int jj = 0; jj < 16; ++jj) {
        int j = g * 16 + jj;
        float a = b1s[j];
#pragma unroll
        for (int k = 0; k < F_IN; ++k) a = fmaf(acc[k], W1s[k * F_HID + j], a);
        float h = fmaxf(a, 0.0f);
        t0 = fmaf(h, W2s[j * F_OUT + 0], t0);
        t1 = fmaf(h, W2s[j * F_OUT + 1], t1);
    }
    t0 += __shfl_xor(t0, 1, 64); t0 += __shfl_xor(t0, 2, 64);
    t1 += __shfl_xor(t1, 1, 64); t1 += __shfl_xor(t1, 2, 64);
    if (g == 0) *(float2*)(ts + (size_t)node * 2) = make_float2(t0 * dv, t1 * dv);
}

// layer-2: 4-lane-per-node gather of ts -> out
__global__ __launch_bounds__(256) void kL2g(const int* __restrict__ bedge,
                                            const int* __restrict__ row_ptr,
                                            const int* __restrict__ gbase,
                                            const int* __restrict__ oflow,
                                            const float* __restrict__ ts,
                                            const float* __restrict__ dinv,
                                            const float* __restrict__ b2,
                                            float* __restrict__ out, int n) {
    const int node = (blockIdx.x * 256 + threadIdx.x) / G;
    const int g = threadIdx.x & (G - 1);
    if (node >= n) return;
    float a0 = 0.0f, a1 = 0.0f;
    const int b = node >> 8;
    if (!oflow[b]) {
        int jb = row_ptr[node], je = row_ptr[node + 1];
        for (int j = jb + g; j < je; j += G) {
            int s = __builtin_nontemporal_load(&bedge[j]);
            float2 t = *(const float2*)(ts + (size_t)s * 2);
            a0 += t.x; a1 += t.y;
        }
    } else {
        int jb = gbase[b], je = gbase[b + 1];
        int dl = node & (BKT - 1);
        for (int j = jb + g; j < je; j += G) {
            unsigned w = (unsigned)__builtin_nontemporal_load(&bedge[j]);
            if ((int)(w >> 20) == dl) {
                int s = (int)(w & 1048575u);
                float2 t = *(const float2*)(ts + (size_t)s * 2);
                a0 += t.x; a1 += t.y;
            }
        }
    }
    a0 += __shfl_xor(a0, 1, 64); a0 += __shfl_xor(a0, 2, 64);
    a1 += __shfl_xor(a1, 1, 64); a1 += __shfl_xor(a1, 2, 64);
    if (g == 0) {
        float dv = dinv[node];
        float2 t = *(const float2*)(ts + (size_t)node * 2);
        *(float2*)(out + (size_t)node * 2) =
            make_float2(b2[0] + (a0 + t.x) * dv, b2[1] + (a1 + t.y) * dv);
    }
}

// ===================== fallback: round-2 CSR path =====================

__global__ void k_zero_i(int* __restrict__ p, int n) {
    int i = blockIdx.x * blockDim.x + threadIdx.x;
    if (i < n) p[i] = 0;
}
__global__ void k_hist(const int* __restrict__ dst, int* __restrict__ counts, int e) {
    int i = blockIdx.x * blockDim.x + threadIdx.x;
    if (i < e) atomicAdd(&counts[dst[i]], 1);
}
__global__ __launch_bounds__(1024) void k_scan(const int* __restrict__ counts,
                                               int* __restrict__ row_ptr,
                                               int* __restrict__ cursor, int n) {
    __shared__ int warp_sums[16];
    __shared__ int carry_s;
    const int tid = threadIdx.x;
    const int lane = tid & 63, wid = tid >> 6;
    if (tid == 0) carry_s = 0;
    __syncthreads();
    for (int base = 0; base < n; base += 1024) {
        int i = base + tid;
        int v = (i < n) ? counts[i] : 0;
        int sv = v;
#pragma unroll
        for (int off = 1; off < 64; off <<= 1) {
            int t = __shfl_up(sv, off, 64);
            if (lane >= off) sv += t;
        }
        if (lane == 63) warp_sums[wid] = sv;
        __syncthreads();
        if (wid == 0 && lane < 16) {
            int ws = warp_sums[lane];
#pragma unroll
            for (int off = 1; off < 16; off <<= 1) {
                int t = __shfl_up(ws, off, 16);
                if (lane >= off) ws += t;
            }
            warp_sums[lane] = ws;
        }
        __syncthreads();
        int wofs = (wid > 0) ? warp_sums[wid - 1] : 0;
        int excl = carry_s + wofs + sv - v;
        if (i < n) { row_ptr[i] = excl; cursor[i] = excl; }
        __syncthreads();
        if (tid == 0) carry_s += warp_sums[15];
        __syncthreads();
    }
    if (tid == 0) row_ptr[n] = carry_s;
}
__global__ void k_fill(const int* __restrict__ src, const int* __restrict__ dst,
                       int* __restrict__ cursor, int* __restrict__ edge_src, int e) {
    int i = blockIdx.x * blockDim.x + threadIdx.x;
    if (i >= e) return;
    int s = src[i], d = dst[i];
    int pos = atomicAdd(&cursor[d], 1);
    edge_src[pos] = s;
}
__global__ void k_dinv_fb(const int* __restrict__ counts, float* __restrict__ dinv, int n) {
    int i = blockIdx.x * blockDim.x + threadIdx.x;
    if (i < n) dinv[i] = rsqrtf(1.0f + (float)counts[i]);
}
__global__ void k_gather_mlp(const int* __restrict__ row_ptr, const int* __restrict__ edge_src,
                             const float* __restrict__ x, const float* __restrict__ dinv,
                             const float* __restrict__ W1, const float* __restrict__ b1,
                             const float* __restrict__ W2, float* __restrict__ ts, int n) {
    __shared__ float W1s[F_IN * F_HID];
    __shared__ float b1s[F_HID];
    __shared__ float W2s[F_HID * F_OUT];
    for (int t = threadIdx.x; t < F_IN * F_HID; t += blockDim.x) W1s[t] = W1[t];
    if (threadIdx.x < F_HID) b1s[threadIdx.x] = b1[threadIdx.x];
    if (threadIdx.x < F_HID * F_OUT) W2s[threadIdx.x] = W2[threadIdx.x];
    __syncthreads();
    int i = blockIdx.x * blockDim.x + threadIdx.x;
    if (i >= n) return;
    float dv = dinv[i];
    float acc[F_IN];
    {
        float d2 = dv * dv;
        const float4* xr = (const float4*)(x + (size_t)i * F_IN);
#pragma unroll
        for (int k = 0; k < 5; ++k) {
            float4 v = xr[k];
            acc[k * 4 + 0] = v.x * d2; acc[k * 4 + 1] = v.y * d2;
            acc[k * 4 + 2] = v.z * d2; acc[k * 4 + 3] = v.w * d2;
        }
    }
    int jb = row_ptr[i], je = row_ptr[i + 1];
    for (int j = jb; j < je; ++j) {
        int s = edge_src[j];
        float w = dinv[s] * dv;
        const float4* xr = (const float4*)(x + (size_t)s * F_IN);
#pragma unroll
        for (int k = 0; k < 5; ++k) {
            float4 v = xr[k];
            acc[k * 4 + 0] = fmaf(v.x, w, acc[k * 4 + 0]);
            acc[k * 4 + 1] = fmaf(v.y, w, acc[k * 4 + 1]);
            acc[k * 4 + 2] = fmaf(v.z, w, acc[k * 4 + 2]);
            acc[k * 4 + 3] = fmaf(v.w, w, acc[k * 4 + 3]);
        }
    }
    float t0 = 0.0f, t1 = 0.0f;
#pragma unroll 8
    for (int j = 0; j < F_HID; ++j) {
        float a = b1s[j];
#pragma unroll
        for (int k = 0; k < F_IN; ++k) a = fmaf(acc[k], W1s[k * F_HID + j], a);
        float h = fmaxf(a, 0.0f);
        t0 = fmaf(h, W2s[j * F_OUT + 0], t0);
        t1 = fmaf(h, W2s[j * F_OUT + 1], t1);
    }
    ts[(size_t)i * 2 + 0] = t0 * dv;
    ts[(size_t)i * 2 + 1] = t1 * dv;
}
__global__ void k_gather2(const int* __restrict__ row_ptr, const int* __restrict__ edge_src,
                          const float* __restrict__ ts, const float* __restrict__ dinv,
                          const float* __restrict__ b2, float* __restrict__ out, int n) {
    int i = blockIdx.x * blockDim.x + threadIdx.x;
    if (i >= n) return;
    float dv = dinv[i];
    float2 t = *(const float2*)(ts + (size_t)i * 2);
    float a0 = t.x, a1 = t.y;
    int jb = row_ptr[i], je = row_ptr[i + 1];
    for (int j = jb; j < je; ++j) {
        int s = edge_src[j];
        float2 v = *(const float2*)(ts + (size_t)s * 2);
        a0 += v.x; a1 += v.y;
    }
    out[(size_t)i * 2 + 0] = b2[0] + a0 * dv;
    out[(size_t)i * 2 + 1] = b2[1] + a1 * dv;
}

// ============================ launch ============================

extern "C" void kernel_launch(void* const* d_in, const int* in_sizes, int n_in,
                              void* d_out, int out_size, void* d_ws, size_t ws_size,
                              hipStream_t stream) {
    const float* x  = (const float*)d_in[0];
    const int*   ei = (const int*)d_in[1];
    const float* W1 = (const float*)d_in[2];
    const float* b1 = (const float*)d_in[3];
    const float* W2 = (const float*)d_in[4];
    const float* b2 = (const float*)d_in[5];
    float* out = (float*)d_out;

    const int n = in_sizes[0] / F_IN;
    const int e = in_sizes[1] / 2;
    const int* src = ei;
    const int* dst = ei + e;

    const int B = 256;
    const int gn = (n + B - 1) / B;
    const int ge = (e + B - 1) / B;

    const int NB = (n + BKT - 1) / BKT;
    // base: gcount NB + gbase NB+1 + gcursor NB + bedge e + row_ptr n+1 + dinv n + ts 2n
    size_t base_words = (size_t)NB * 3 + 1 + (size_t)e + (size_t)(n + 1) + 3 * (size_t)n;
    size_t need_b   = base_words * 4;
    size_t need_h40 = need_b + (size_t)n * 40;
    // 64B path: xh must be 16B aligned; base_words is a multiple of words anyway, align up.
    size_t xh_off_words = (base_words + 3) & ~(size_t)3;
    size_t need_h64 = xh_off_words * 4 + (size_t)n * 64;

    if (n < (1 << 20) && NB <= MAXNB && ws_size >= need_b) {
        int*   gcount  = (int*)d_ws;                // NB
        int*   gbase   = gcount + NB;               // NB+1
        int*   gcursor = gbase + NB + 1;            // NB (reused as oflow after kA2)
        int*   bedge   = gcursor + NB;              // e
        int*   row_ptr = bedge + e;                 // n+1
        float* dinv    = (float*)(row_ptr + n + 1); // n
        float* ts      = dinv + n;                  // 2n
        int*   oflow   = gcursor;

        kz<<<(NB + 255) / 256, 256, 0, stream>>>(gcount, NB);
        kA0<<<NWG_A, 256, 0, stream>>>(dst, gcount, e);
        kscan_p<<<1, 256, 0, stream>>>(gcount, gbase, gcursor, row_ptr, NB, n);
        kA2<<<(e + CHUNK - 1) / CHUNK, 256, 0, stream>>>(src, dst, gcursor, bedge, e, NB);
        kB<<<NB, 256, 0, stream>>>(bedge, gbase, row_ptr, oflow, dinv, n);
        int gg4 = ((size_t)n * G + 255) / 256;
        int gg8 = ((size_t)n * G8 + 255) / 256;
        if (ws_size >= need_h64) {
            uint4* xh64 = (uint4*)((int*)d_ws + xh_off_words);
            kxh64<<<gn, B, 0, stream>>>(x, dinv, xh64, n);
            kAgg_h64<<<gg8, 256, 0, stream>>>(bedge, row_ptr, gbase, oflow, x, xh64, dinv,
                                              W1, b1, W2, ts, n);
        } else if (ws_size >= need_h40) {
            unsigned* xh40 = (unsigned*)(ts + 2 * (size_t)n);
            kxh<<<gn, B, 0, stream>>>(x, dinv, xh40, n);
            kAgg_h<<<gg4, 256, 0, stream>>>(bedge, row_ptr, gbase, oflow, x, xh40, dinv,
                                            W1, b1, W2, ts, n);
        } else {
            kAgg<<<gg4, 256, 0, stream>>>(bedge, row_ptr, gbase, oflow, x, dinv,
                                          W1, b1, W2, ts, n);
        }
        kL2g<<<gg4, 256, 0, stream>>>(bedge, row_ptr, gbase, oflow, ts, dinv, b2, out, n);
    } else {
        int*   counts   = (int*)d_ws;
        int*   row_ptr  = counts + n;
        int*   cursor   = row_ptr + n + 1;
        int*   edge_src = cursor + n;
        float* dinv     = (float*)(edge_src + e);
        float* ts       = dinv + n;

        k_zero_i<<<gn, B, 0, stream>>>(counts, n);
        k_hist<<<ge, B, 0, stream>>>(dst, counts, e);
        k_scan<<<1, 1024, 0, stream>>>(counts, row_ptr, cursor, n);
        k_fill<<<ge, B, 0, stream>>>(src, dst, cursor, edge_src, e);
        k_dinv_fb<<<gn, B, 0, stream>>>(counts, dinv, n);
        k_gather_mlp<<<gn, B, 0, stream>>>(row_ptr, edge_src, x, dinv, W1, b1, W2, ts, n);
        k_gather2<<<gn, B, 0, stream>>>(row_ptr, edge_src, ts, dinv, b2, out, n);
    }
}

// Round 7
// 188.923 us; speedup vs baseline: 20.0056x; 1.0699x over previous
//
#include <hip/hip_runtime.h>
#include <hip/hip_fp16.h>

#define F_IN 20
#define F_HID 64
#define F_OUT 2
#define BKT 256        // nodes per bucket
#define MAXNB 512      // max buckets the LDS arrays support
#define NWG_A 512      // kA0 histogram workgroups
#define STAGE_MAX 14336 // per-bucket LDS edge staging capacity (56 KB)
#define G8 8           // lanes per node in gather kernels
#define CHUNK 4096     // edges per WG in kA2
#define PAD 16         // ints per global atomic bin (one 64B line) -- kills same-line
                       // atomic serialization across WGs/XCDs

// ===================== bucketed + sorted path =====================

__global__ void kz(int* __restrict__ g, int m) {
    int i = blockIdx.x * blockDim.x + threadIdx.x;
    if (i < m) g[i] = 0;
}

// coarse histogram of dst>>8 (LDS-aggregated, merged into line-padded bins)
__global__ __launch_bounds__(256) void kA0(const int* __restrict__ dst,
                                           int* __restrict__ gcount, int e) {
    __shared__ int c[MAXNB];
    for (int t = threadIdx.x; t < MAXNB; t += 256) c[t] = 0;
    __syncthreads();
    int stride = gridDim.x * blockDim.x;
    for (int i = blockIdx.x * blockDim.x + threadIdx.x; i < e; i += stride)
        atomicAdd(&c[dst[i] >> 8], 1);
    __syncthreads();
    for (int t = threadIdx.x; t < MAXNB; t += 256)
        if (c[t]) atomicAdd(&gcount[t * PAD], c[t]);
}

// parallel exclusive scan over nb<=512 line-padded bins (one 256-thread WG)
__global__ __launch_bounds__(256) void kscan_p(const int* __restrict__ gcount,
                                               int* __restrict__ gbase,
                                               int* __restrict__ gcursor,
                                               int* __restrict__ row_ptr,
                                               int nb, int n) {
    __shared__ int wtot[4];
    const int tid = threadIdx.x;
    const int t2 = tid * 2;
    int v0 = (t2 < nb) ? gcount[t2 * PAD] : 0;
    int v1 = (t2 + 1 < nb) ? gcount[(t2 + 1) * PAD] : 0;
    int pv = v0 + v1;
    int sv = pv;
#pragma unroll
    for (int off = 1; off < 64; off <<= 1) {
        int u = __shfl_up(sv, off, 64);
        if ((tid & 63) >= off) sv += u;
    }
    if ((tid & 63) == 63) wtot[tid >> 6] = sv;
    __syncthreads();
    int wo = 0;
    for (int w = 0; w < (tid >> 6); ++w) wo += wtot[w];
    int excl = wo + sv - pv;
    if (t2 < nb)     { gbase[t2] = excl;          gcursor[t2 * PAD] = excl; }
    if (t2 + 1 < nb) { gbase[t2 + 1] = excl + v0; gcursor[(t2 + 1) * PAD] = excl + v0; }
    if (tid == 0) {
        int total = wtot[0] + wtot[1] + wtot[2] + wtot[3];
        gbase[nb] = total;
        row_ptr[n] = total;
    }
}

// LDS-reorder scatter: chunk -> local counting sort by bucket -> coalesced run writes
__global__ __launch_bounds__(256) void kA2(const int* __restrict__ src,
                                           const int* __restrict__ dst,
                                           int* __restrict__ gcursor,
                                           int* __restrict__ bedge, int e, int nb) {
    __shared__ int stage[CHUNK];
    __shared__ unsigned short bkt[CHUNK];
    __shared__ unsigned short inv[CHUNK];
    __shared__ int cnt[MAXNB];
    __shared__ int lbase[MAXNB];
    __shared__ int lcur[MAXNB];
    __shared__ int gclaim[MAXNB];
    __shared__ int wtot[4];
    const int tid = threadIdx.x;
    const int lo = blockIdx.x * CHUNK;
    const int hi = min(e, lo + CHUNK);
    const int cn = hi - lo;
    for (int t = tid; t < MAXNB; t += 256) cnt[t] = 0;
    __syncthreads();
    for (int j = tid; j < cn; j += 256) {
        int d = dst[lo + j], s = src[lo + j];
        int b = d >> 8;
        stage[j] = ((d & (BKT - 1)) << 20) | s;
        bkt[j] = (unsigned short)b;
        atomicAdd(&cnt[b], 1);
    }
    __syncthreads();
    const int t2 = tid * 2;
    int v0 = cnt[t2], v1 = cnt[t2 + 1];
    int pv = v0 + v1;
    int sv = pv;
#pragma unroll
    for (int off = 1; off < 64; off <<= 1) {
        int u = __shfl_up(sv, off, 64);
        if ((tid & 63) >= off) sv += u;
    }
    if ((tid & 63) == 63) wtot[tid >> 6] = sv;
    __syncthreads();
    int wo = 0;
    for (int w = 0; w < (tid >> 6); ++w) wo += wtot[w];
    int excl = wo + sv - pv;
    lbase[t2] = excl;          lcur[t2] = excl;
    lbase[t2 + 1] = excl + v0; lcur[t2 + 1] = excl + v0;
    if (v0 && t2 < nb)     gclaim[t2]     = atomicAdd(&gcursor[t2 * PAD], v0);
    if (v1 && t2 + 1 < nb) gclaim[t2 + 1] = atomicAdd(&gcursor[(t2 + 1) * PAD], v1);
    __syncthreads();
    for (int j = tid; j < cn; j += 256) {
        int p = atomicAdd(&lcur[bkt[j]], 1);
        inv[p] = (unsigned short)j;
    }
    __syncthreads();
    for (int t = tid; t < cn; t += 256) {
        int j = inv[t];
        int b = bkt[j];
        bedge[gclaim[b] + (t - lbase[b])] = stage[j];
    }
}

// per-bucket in-LDS counting sort -> dst-sorted src list (in place), row_ptr, dinv
__global__ __launch_bounds__(256) void kB(int* __restrict__ bedge,
                                          const int* __restrict__ gbase,
                                          int* __restrict__ row_ptr,
                                          int* __restrict__ oflow,
                                          float* __restrict__ dinv, int n) {
    __shared__ int stage[STAGE_MAX];
    __shared__ int hist[BKT];
    __shared__ int cur[BKT];
    __shared__ int wsum[4];
    const int tid = threadIdx.x, b = blockIdx.x;
    const int lo = gbase[b], hi = gbase[b + 1], cnt = hi - lo;
    hist[tid] = 0;
    __syncthreads();
    const bool staged = (cnt <= STAGE_MAX);
    if (staged) {
        for (int j = tid; j < cnt; j += 256) {
            int w = bedge[lo + j];
            stage[j] = w;
            atomicAdd(&hist[((unsigned)w) >> 20], 1);
        }
    } else {
        for (int j = tid; j < cnt; j += 256)
            atomicAdd(&hist[((unsigned)bedge[lo + j]) >> 20], 1);
    }
    if (tid == 0) oflow[b] = staged ? 0 : 1;
    __syncthreads();
    int v = hist[tid];
    int sv = v;
#pragma unroll
    for (int off = 1; off < 64; off <<= 1) {
        int t = __shfl_up(sv, off, 64);
        if ((tid & 63) >= off) sv += t;
    }
    if ((tid & 63) == 63) wsum[tid >> 6] = sv;
    __syncthreads();
    int wo = 0;
    for (int w = 0; w < (tid >> 6); ++w) wo += wsum[w];
    int excl = wo + sv - v;
    cur[tid] = excl;
    int node = (b << 8) + tid;
    if (node < n) {
        row_ptr[node] = lo + excl;
        dinv[node] = rsqrtf(1.0f + (float)v);
    }
    __syncthreads();
    if (staged) {
        for (int j = tid; j < cnt; j += 256) {
            int w = stage[j];
            int pos = atomicAdd(&cur[((unsigned)w) >> 20], 1);
            bedge[lo + pos] = w & 1048575;
        }
    }
}

// xh64[i] = fp16(x[i]*dinv[i]) padded to 64B/row (4 x uint4)
__global__ __launch_bounds__(256) void kxh64(const float* __restrict__ x,
                                             const float* __restrict__ dinv,
                                             uint4* __restrict__ xh, int n) {
    int i = blockIdx.x * blockDim.x + threadIdx.x;
    if (i >= n) return;
    float dv = dinv[i];
    const float4* xr = (const float4*)(x + (size_t)i * F_IN);
    unsigned w[10];
#pragma unroll
    for (int k = 0; k < 5; ++k) {
        float4 v = xr[k];
        __half2 h0 = __float22half2_rn(make_float2(v.x * dv, v.y * dv));
        __half2 h1 = __float22half2_rn(make_float2(v.z * dv, v.w * dv));
        w[k * 2 + 0] = *(const unsigned*)&h0;
        w[k * 2 + 1] = *(const unsigned*)&h1;
    }
    uint4* o = xh + (size_t)i * 4;
    o[0] = make_uint4(w[0], w[1], w[2], w[3]);
    o[1] = make_uint4(w[4], w[5], w[6], w[7]);
    o[2] = make_uint4(w[8], w[9], 0u, 0u);
    o[3] = make_uint4(0u, 0u, 0u, 0u);
}

#define ACC2(u, idx) { float2 f_ = __half22float2(*(const __half2*)&(u)); \
                       acc[idx] += f_.x; acc[idx + 1] += f_.y; }

// layer-1 (64B fp16 table): 8-lane-per-node, TWO src-range sweeps so each
// sweep's gather working set (3.2MB) fits one XCD's 4MB L2.
__global__ __launch_bounds__(256) void kAgg_h64(const int* __restrict__ bedge,
                                                const int* __restrict__ row_ptr,
                                                const int* __restrict__ gbase,
                                                const int* __restrict__ oflow,
                                                const float* __restrict__ x,
                                                const uint4* __restrict__ xh,
                                                const float* __restrict__ dinv,
                                                const float* __restrict__ W1,
                                                const float* __restrict__ b1,
                                                const float* __restrict__ W2,
                                                float* __restrict__ ts, int n) {
    __shared__ float W1s[F_IN * F_HID];
    __shared__ float b1s[F_HID];
    __shared__ float W2s[F_HID * F_OUT];
    for (int t = threadIdx.x; t < F_IN * F_HID; t += 256) W1s[t] = W1[t];
    if (threadIdx.x < F_HID) b1s[threadIdx.x] = b1[threadIdx.x];
    if (threadIdx.x < F_HID * F_OUT) W2s[threadIdx.x] = W2[threadIdx.x];
    __syncthreads();
    const int node = (blockIdx.x * 256 + threadIdx.x) >> 3;
    const int g = threadIdx.x & (G8 - 1);
    if (node >= n) return;
    const float dv = dinv[node];
    float acc[F_IN];
#pragma unroll
    for (int k = 0; k < F_IN; ++k) acc[k] = 0.0f;
    const int b = node >> 8;
    const int half = n >> 1;
    if (!oflow[b]) {
        int jb = row_ptr[node], je = row_ptr[node + 1];
#pragma unroll 1
        for (int sweep = 0; sweep < 2; ++sweep) {
            int slo = sweep ? half : 0;
            int shi = sweep ? n : half;
            for (int j = jb + g; j < je; j += G8) {
                int s = __builtin_nontemporal_load(&bedge[j]);
                if (s >= slo && s < shi) {
                    const uint4* r = xh + (size_t)s * 4;
                    uint4 q0 = r[0], q1 = r[1], q2 = r[2];
                    ACC2(q0.x, 0)  ACC2(q0.y, 2)  ACC2(q0.z, 4)  ACC2(q0.w, 6)
                    ACC2(q1.x, 8)  ACC2(q1.y, 10) ACC2(q1.z, 12) ACC2(q1.w, 14)
                    ACC2(q2.x, 16) ACC2(q2.y, 18)
                }
            }
        }
    } else {  // unsorted flagged bucket: scan whole bucket, filter on dl
        int jb = gbase[b], je = gbase[b + 1];
        int dl = node & (BKT - 1);
        for (int j = jb + g; j < je; j += G8) {
            unsigned w = (unsigned)__builtin_nontemporal_load(&bedge[j]);
            if ((int)(w >> 20) == dl) {
                int s = (int)(w & 1048575u);
                const uint4* r = xh + (size_t)s * 4;
                uint4 q0 = r[0], q1 = r[1], q2 = r[2];
                ACC2(q0.x, 0)  ACC2(q0.y, 2)  ACC2(q0.z, 4)  ACC2(q0.w, 6)
                ACC2(q1.x, 8)  ACC2(q1.y, 10) ACC2(q1.z, 12) ACC2(q1.w, 14)
                ACC2(q2.x, 16) ACC2(q2.y, 18)
            }
        }
    }
    if (g == 0) {  // self-loop term exact fp32: x[node]*dv
        const float4* xr = (const float4*)(x + (size_t)node * F_IN);
#pragma unroll
        for (int k = 0; k < 5; ++k) {
            float4 vv = xr[k];
            acc[k * 4 + 0] = fmaf(vv.x, dv, acc[k * 4 + 0]);
            acc[k * 4 + 1] = fmaf(vv.y, dv, acc[k * 4 + 1]);
            acc[k * 4 + 2] = fmaf(vv.z, dv, acc[k * 4 + 2]);
            acc[k * 4 + 3] = fmaf(vv.w, dv, acc[k * 4 + 3]);
        }
    }
#pragma unroll
    for (int k = 0; k < F_IN; ++k) {
        acc[k] += __shfl_xor(acc[k], 1, 64);
        acc[k] += __shfl_xor(acc[k], 2, 64);
        acc[k] += __shfl_xor(acc[k], 4, 64);
        acc[k] *= dv;
    }
    float t0 = 0.0f, t1 = 0.0f;  // lane g: hidden units [g*8, g*8+8)
#pragma unroll
    for (int jj = 0; jj < 8; ++jj) {
        int j = g * 8 + jj;
        float a = b1s[j];
#pragma unroll
        for (int k = 0; k < F_IN; ++k) a = fmaf(acc[k], W1s[k * F_HID + j], a);
        float h = fmaxf(a, 0.0f);
        t0 = fmaf(h, W2s[j * F_OUT + 0], t0);
        t1 = fmaf(h, W2s[j * F_OUT + 1], t1);
    }
    t0 += __shfl_xor(t0, 1, 64); t0 += __shfl_xor(t0, 2, 64); t0 += __shfl_xor(t0, 4, 64);
    t1 += __shfl_xor(t1, 1, 64); t1 += __shfl_xor(t1, 2, 64); t1 += __shfl_xor(t1, 4, 64);
    if (g == 0) *(float2*)(ts + (size_t)node * 2) = make_float2(t0 * dv, t1 * dv);
}

// layer-1 fp32 fallback (no xh table)
__global__ __launch_bounds__(256) void kAgg(const int* __restrict__ bedge,
                                            const int* __restrict__ row_ptr,
                                            const int* __restrict__ gbase,
                                            const int* __restrict__ oflow,
                                            const float* __restrict__ x,
                                            const float* __restrict__ dinv,
                                            const float* __restrict__ W1,
                                            const float* __restrict__ b1,
                                            const float* __restrict__ W2,
                                            float* __restrict__ ts, int n) {
    __shared__ float W1s[F_IN * F_HID];
    __shared__ float b1s[F_HID];
    __shared__ float W2s[F_HID * F_OUT];
    for (int t = threadIdx.x; t < F_IN * F_HID; t += 256) W1s[t] = W1[t];
    if (threadIdx.x < F_HID) b1s[threadIdx.x] = b1[threadIdx.x];
    if (threadIdx.x < F_HID * F_OUT) W2s[threadIdx.x] = W2[threadIdx.x];
    __syncthreads();
    const int node = (blockIdx.x * 256 + threadIdx.x) >> 3;
    const int g = threadIdx.x & (G8 - 1);
    if (node >= n) return;
    const float dv = dinv[node];
    float acc[F_IN];
#pragma unroll
    for (int k = 0; k < F_IN; ++k) acc[k] = 0.0f;
    const int b = node >> 8;
    if (!oflow[b]) {
        int jb = row_ptr[node], je = row_ptr[node + 1];
        for (int j = jb + g; j < je; j += G8) {
            int s = bedge[j];
            float w = dinv[s];
            const float4* xr = (const float4*)(x + (size_t)s * F_IN);
#pragma unroll
            for (int k = 0; k < 5; ++k) {
                float4 vv = xr[k];
                acc[k * 4 + 0] = fmaf(vv.x, w, acc[k * 4 + 0]);
                acc[k * 4 + 1] = fmaf(vv.y, w, acc[k * 4 + 1]);
                acc[k * 4 + 2] = fmaf(vv.z, w, acc[k * 4 + 2]);
                acc[k * 4 + 3] = fmaf(vv.w, w, acc[k * 4 + 3]);
            }
        }
    } else {
        int jb = gbase[b], je = gbase[b + 1];
        int dl = node & (BKT - 1);
        for (int j = jb + g; j < je; j += G8) {
            unsigned w = (unsigned)bedge[j];
            if ((int)(w >> 20) == dl) {
                int s = (int)(w & 1048575u);
                float ww = dinv[s];
                const float4* xr = (const float4*)(x + (size_t)s * F_IN);
#pragma unroll
                for (int k = 0; k < 5; ++k) {
                    float4 vv = xr[k];
                    acc[k * 4 + 0] = fmaf(vv.x, ww, acc[k * 4 + 0]);
                    acc[k * 4 + 1] = fmaf(vv.y, ww, acc[k * 4 + 1]);
                    acc[k * 4 + 2] = fmaf(vv.z, ww, acc[k * 4 + 2]);
                    acc[k * 4 + 3] = fmaf(vv.w, ww, acc[k * 4 + 3]);
                }
            }
        }
    }
    if (g == 0) {
        const float4* xr = (const float4*)(x + (size_t)node * F_IN);
#pragma unroll
        for (int k = 0; k < 5; ++k) {
            float4 vv = xr[k];
            acc[k * 4 + 0] = fmaf(vv.x, dv, acc[k * 4 + 0]);
            acc[k * 4 + 1] = fmaf(vv.y, dv, acc[k * 4 + 1]);
            acc[k * 4 + 2] = fmaf(vv.z, dv, acc[k * 4 + 2]);
            acc[k * 4 + 3] = fmaf(vv.w, dv, acc[k * 4 + 3]);
        }
    }
#pragma unroll
    for (int k = 0; k < F_IN; ++k) {
        acc[k] += __shfl_xor(acc[k], 1, 64);
        acc[k] += __shfl_xor(acc[k], 2, 64);
        acc[k] += __shfl_xor(acc[k], 4, 64);
        acc[k] *= dv;
    }
    float t0 = 0.0f, t1 = 0.0f;
#pragma unroll
    for (int jj = 0; jj < 8; ++jj) {
        int j = g * 8 + jj;
        float a = b1s[j];
#pragma unroll
        for (int k = 0; k < F_IN; ++k) a = fmaf(acc[k], W1s[k * F_HID + j], a);
        float h = fmaxf(a, 0.0f);
        t0 = fmaf(h, W2s[j * F_OUT + 0], t0);
        t1 = fmaf(h, W2s[j * F_OUT + 1], t1);
    }
    t0 += __shfl_xor(t0, 1, 64); t0 += __shfl_xor(t0, 2, 64); t0 += __shfl_xor(t0, 4, 64);
    t1 += __shfl_xor(t1, 1, 64); t1 += __shfl_xor(t1, 2, 64); t1 += __shfl_xor(t1, 4, 64);
    if (g == 0) *(float2*)(ts + (size_t)node * 2) = make_float2(t0 * dv, t1 * dv);
}

// layer-2: 8-lane-per-node gather of ts -> out (ts table 800KB, L2-resident)
__global__ __launch_bounds__(256) void kL2g(const int* __restrict__ bedge,
                                            const int* __restrict__ row_ptr,
                                            const int* __restrict__ gbase,
                                            const int* __restrict__ oflow,
                                            const float* __restrict__ ts,
                                            const float* __restrict__ dinv,
                                            const float* __restrict__ b2,
                                            float* __restrict__ out, int n) {
    const int node = (blockIdx.x * 256 + threadIdx.x) >> 3;
    const int g = threadIdx.x & (G8 - 1);
    if (node >= n) return;
    float a0 = 0.0f, a1 = 0.0f;
    const int b = node >> 8;
    if (!oflow[b]) {
        int jb = row_ptr[node], je = row_ptr[node + 1];
        for (int j = jb + g; j < je; j += G8) {
            int s = __builtin_nontemporal_load(&bedge[j]);
            float2 t = *(const float2*)(ts + (size_t)s * 2);
            a0 += t.x; a1 += t.y;
        }
    } else {
        int jb = gbase[b], je = gbase[b + 1];
        int dl = node & (BKT - 1);
        for (int j = jb + g; j < je; j += G8) {
            unsigned w = (unsigned)__builtin_nontemporal_load(&bedge[j]);
            if ((int)(w >> 20) == dl) {
                int s = (int)(w & 1048575u);
                float2 t = *(const float2*)(ts + (size_t)s * 2);
                a0 += t.x; a1 += t.y;
            }
        }
    }
    a0 += __shfl_xor(a0, 1, 64); a0 += __shfl_xor(a0, 2, 64); a0 += __shfl_xor(a0, 4, 64);
    a1 += __shfl_xor(a1, 1, 64); a1 += __shfl_xor(a1, 2, 64); a1 += __shfl_xor(a1, 4, 64);
    if (g == 0) {
        float dv = dinv[node];
        float2 t = *(const float2*)(ts + (size_t)node * 2);
        *(float2*)(out + (size_t)node * 2) =
            make_float2(b2[0] + (a0 + t.x) * dv, b2[1] + (a1 + t.y) * dv);
    }
}

// ===================== fallback: round-2 CSR path =====================

__global__ void k_zero_i(int* __restrict__ p, int n) {
    int i = blockIdx.x * blockDim.x + threadIdx.x;
    if (i < n) p[i] = 0;
}
__global__ void k_hist(const int* __restrict__ dst, int* __restrict__ counts, int e) {
    int i = blockIdx.x * blockDim.x + threadIdx.x;
    if (i < e) atomicAdd(&counts[dst[i]], 1);
}
__global__ __launch_bounds__(1024) void k_scan(const int* __restrict__ counts,
                                               int* __restrict__ row_ptr,
                                               int* __restrict__ cursor, int n) {
    __shared__ int warp_sums[16];
    __shared__ int carry_s;
    const int tid = threadIdx.x;
    const int lane = tid & 63, wid = tid >> 6;
    if (tid == 0) carry_s = 0;
    __syncthreads();
    for (int base = 0; base < n; base += 1024) {
        int i = base + tid;
        int v = (i < n) ? counts[i] : 0;
        int sv = v;
#pragma unroll
        for (int off = 1; off < 64; off <<= 1) {
            int t = __shfl_up(sv, off, 64);
            if (lane >= off) sv += t;
        }
        if (lane == 63) warp_sums[wid] = sv;
        __syncthreads();
        if (wid == 0 && lane < 16) {
            int ws = warp_sums[lane];
#pragma unroll
            for (int off = 1; off < 16; off <<= 1) {
                int t = __shfl_up(ws, off, 16);
                if (lane >= off) ws += t;
            }
            warp_sums[lane] = ws;
        }
        __syncthreads();
        int wofs = (wid > 0) ? warp_sums[wid - 1] : 0;
        int excl = carry_s + wofs + sv - v;
        if (i < n) { row_ptr[i] = excl; cursor[i] = excl; }
        __syncthreads();
        if (tid == 0) carry_s += warp_sums[15];
        __syncthreads();
    }
    if (tid == 0) row_ptr[n] = carry_s;
}
__global__ void k_fill(const int* __restrict__ src, const int* __restrict__ dst,
                       int* __restrict__ cursor, int* __restrict__ edge_src, int e) {
    int i = blockIdx.x * blockDim.x + threadIdx.x;
    if (i >= e) return;
    int s = src[i], d = dst[i];
    int pos = atomicAdd(&cursor[d], 1);
    edge_src[pos] = s;
}
__global__ void k_dinv_fb(const int* __restrict__ counts, float* __restrict__ dinv, int n) {
    int i = blockIdx.x * blockDim.x + threadIdx.x;
    if (i < n) dinv[i] = rsqrtf(1.0f + (float)counts[i]);
}
__global__ void k_gather_mlp(const int* __restrict__ row_ptr, const int* __restrict__ edge_src,
                             const float* __restrict__ x, const float* __restrict__ dinv,
                             const float* __restrict__ W1, const float* __restrict__ b1,
                             const float* __restrict__ W2, float* __restrict__ ts, int n) {
    __shared__ float W1s[F_IN * F_HID];
    __shared__ float b1s[F_HID];
    __shared__ float W2s[F_HID * F_OUT];
    for (int t = threadIdx.x; t < F_IN * F_HID; t += blockDim.x) W1s[t] = W1[t];
    if (threadIdx.x < F_HID) b1s[threadIdx.x] = b1[threadIdx.x];
    if (threadIdx.x < F_HID * F_OUT) W2s[threadIdx.x] = W2[threadIdx.x];
    __syncthreads();
    int i = blockIdx.x * blockDim.x + threadIdx.x;
    if (i >= n) return;
    float dv = dinv[i];
    float acc[F_IN];
    {
        float d2 = dv * dv;
        const float4* xr = (const float4*)(x + (size_t)i * F_IN);
#pragma unroll
        for (int k = 0; k < 5; ++k) {
            float4 v = xr[k];
            acc[k * 4 + 0] = v.x * d2; acc[k * 4 + 1] = v.y * d2;
            acc[k * 4 + 2] = v.z * d2; acc[k * 4 + 3] = v.w * d2;
        }
    }
    int jb = row_ptr[i], je = row_ptr[i + 1];
    for (int j = jb; j < je; ++j) {
        int s = edge_src[j];
        float w = dinv[s] * dv;
        const float4* xr = (const float4*)(x + (size_t)s * F_IN);
#pragma unroll
        for (int k = 0; k < 5; ++k) {
            float4 v = xr[k];
            acc[k * 4 + 0] = fmaf(v.x, w, acc[k * 4 + 0]);
            acc[k * 4 + 1] = fmaf(v.y, w, acc[k * 4 + 1]);
            acc[k * 4 + 2] = fmaf(v.z, w, acc[k * 4 + 2]);
            acc[k * 4 + 3] = fmaf(v.w, w, acc[k * 4 + 3]);
        }
    }
    float t0 = 0.0f, t1 = 0.0f;
#pragma unroll 8
    for (int j = 0; j < F_HID; ++j) {
        float a = b1s[j];
#pragma unroll
        for (int k = 0; k < F_IN; ++k) a = fmaf(acc[k], W1s[k * F_HID + j], a);
        float h = fmaxf(a, 0.0f);
        t0 = fmaf(h, W2s[j * F_OUT + 0], t0);
        t1 = fmaf(h, W2s[j * F_OUT + 1], t1);
    }
    ts[(size_t)i * 2 + 0] = t0 * dv;
    ts[(size_t)i * 2 + 1] = t1 * dv;
}
__global__ void k_gather2(const int* __restrict__ row_ptr, const int* __restrict__ edge_src,
                          const float* __restrict__ ts, const float* __restrict__ dinv,
                          const float* __restrict__ b2, float* __restrict__ out, int n) {
    int i = blockIdx.x * blockDim.x + threadIdx.x;
    if (i >= n) return;
    float dv = dinv[i];
    float2 t = *(const float2*)(ts + (size_t)i * 2);
    float a0 = t.x, a1 = t.y;
    int jb = row_ptr[i], je = row_ptr[i + 1];
    for (int j = jb; j < je; ++j) {
        int s = edge_src[j];
        float2 v = *(const float2*)(ts + (size_t)s * 2);
        a0 += v.x; a1 += v.y;
    }
    out[(size_t)i * 2 + 0] = b2[0] + a0 * dv;
    out[(size_t)i * 2 + 1] = b2[1] + a1 * dv;
}

// ============================ launch ============================

extern "C" void kernel_launch(void* const* d_in, const int* in_sizes, int n_in,
                              void* d_out, int out_size, void* d_ws, size_t ws_size,
                              hipStream_t stream) {
    const float* x  = (const float*)d_in[0];
    const int*   ei = (const int*)d_in[1];
    const float* W1 = (const float*)d_in[2];
    const float* b1 = (const float*)d_in[3];
    const float* W2 = (const float*)d_in[4];
    const float* b2 = (const float*)d_in[5];
    float* out = (float*)d_out;

    const int n = in_sizes[0] / F_IN;
    const int e = in_sizes[1] / 2;
    const int* src = ei;
    const int* dst = ei + e;

    const int B = 256;
    const int gn = (n + B - 1) / B;
    const int ge = (e + B - 1) / B;

    const int NB = (n + BKT - 1) / BKT;
    // layout: gcount NB*PAD | gcursor NB*PAD | gbase NB+1 | bedge e | row_ptr n+1
    //         | dinv n | ts 2n | [align16] xh 16n words
    size_t base_words = (size_t)NB * PAD * 2 + (size_t)(NB + 1) + (size_t)e
                      + (size_t)(n + 1) + 3 * (size_t)n;
    size_t need_b = base_words * 4;
    size_t xh_off_words = (base_words + 3) & ~(size_t)3;
    size_t need_h64 = xh_off_words * 4 + (size_t)n * 64;

    if (n < (1 << 20) && NB <= MAXNB && ws_size >= need_b) {
        int*   gcount  = (int*)d_ws;                  // NB*PAD (line-padded bins)
        int*   gcursor = gcount + (size_t)NB * PAD;   // NB*PAD
        int*   gbase   = gcursor + (size_t)NB * PAD;  // NB+1
        int*   bedge   = gbase + NB + 1;              // e
        int*   row_ptr = bedge + e;                   // n+1
        float* dinv    = (float*)(row_ptr + n + 1);   // n
        float* ts      = dinv + n;                    // 2n
        int*   oflow   = gcount;                      // reuse after kscan_p

        kz<<<(NB * PAD + 255) / 256, 256, 0, stream>>>(gcount, NB * PAD);
        kA0<<<NWG_A, 256, 0, stream>>>(dst, gcount, e);
        kscan_p<<<1, 256, 0, stream>>>(gcount, gbase, gcursor, row_ptr, NB, n);
        kA2<<<(e + CHUNK - 1) / CHUNK, 256, 0, stream>>>(src, dst, gcursor, bedge, e, NB);
        kB<<<NB, 256, 0, stream>>>(bedge, gbase, row_ptr, oflow, dinv, n);
        int gg8 = ((size_t)n * G8 + 255) / 256;
        if (ws_size >= need_h64) {
            uint4* xh64 = (uint4*)((int*)d_ws + xh_off_words);
            kxh64<<<gn, B, 0, stream>>>(x, dinv, xh64, n);
            kAgg_h64<<<gg8, 256, 0, stream>>>(bedge, row_ptr, gbase, oflow, x, xh64, dinv,
                                              W1, b1, W2, ts, n);
        } else {
            kAgg<<<gg8, 256, 0, stream>>>(bedge, row_ptr, gbase, oflow, x, dinv,
                                          W1, b1, W2, ts, n);
        }
        kL2g<<<gg8, 256, 0, stream>>>(bedge, row_ptr, gbase, oflow, ts, dinv, b2, out, n);
    } else {
        int*   counts   = (int*)d_ws;
        int*   row_ptr  = counts + n;
        int*   cursor   = row_ptr + n + 1;
        int*   edge_src = cursor + n;
        float* dinv     = (float*)(edge_src + e);
        float* ts       = dinv + n;

        k_zero_i<<<gn, B, 0, stream>>>(counts, n);
        k_hist<<<ge, B, 0, stream>>>(dst, counts, e);
        k_scan<<<1, 1024, 0, stream>>>(counts, row_ptr, cursor, n);
        k_fill<<<ge, B, 0, stream>>>(src, dst, cursor, edge_src, e);
        k_dinv_fb<<<gn, B, 0, stream>>>(counts, dinv, n);
        k_gather_mlp<<<gn, B, 0, stream>>>(row_ptr, edge_src, x, dinv, W1, b1, W2, ts, n);
        k_gather2<<<gn, B, 0, stream>>>(row_ptr, edge_src, ts, dinv, b2, out, n);
    }
}